// Round 1
// baseline (637.963 us; speedup 1.0000x reference)
//
#include <hip/hip_runtime.h>
#include <hip/hip_bf16.h>
#include <math.h>

#define SEQ 2048
#define BATCH 4
#define MROWS (BATCH*SEQ)     // 8192
#define DMODEL 1024
#define NHEADS 16
#define DKH 64

typedef float f32x4 __attribute__((ext_vector_type(4)));
typedef __bf16 bf16x8 __attribute__((ext_vector_type(8)));
typedef unsigned short u16;
typedef u16 u16x4 __attribute__((ext_vector_type(4)));
typedef u16 u16x8 __attribute__((ext_vector_type(8)));

__device__ __forceinline__ u16 f2bf(float f) {
  union { float f; unsigned u; } v; v.f = f;
  unsigned r = v.u + 0x7FFFu + ((v.u >> 16) & 1u);
  return (u16)(r >> 16);
}

__device__ __forceinline__ void async_copy16(const void* g, void* l) {
  __builtin_amdgcn_global_load_lds(
      (const __attribute__((address_space(1))) void*)g,
      (__attribute__((address_space(3))) void*)l, 16, 0, 0);
}

// ---------------- f32 -> bf16 convert (vectorized) ----------------
__global__ __launch_bounds__(256) void k_cvt(const float* __restrict__ in,
                                             u16* __restrict__ out, int n4) {
  int i = blockIdx.x * 256 + threadIdx.x;
  if (i >= n4) return;
  float4 v = ((const float4*)in)[i];
  u16x4 o;
  o[0] = f2bf(v.x); o[1] = f2bf(v.y); o[2] = f2bf(v.z); o[3] = f2bf(v.w);
  ((u16x4*)out)[i] = o;
}

// ---------------- RoPE tables: cos/sin[s][j], j in [0,32) ----------------
__global__ __launch_bounds__(256) void k_rope_tab(const int* __restrict__ pos,
                                                  float* __restrict__ cosT,
                                                  float* __restrict__ sinT) {
  int i = blockIdx.x * 256 + threadIdx.x;   // SEQ*32 = 65536 total
  int s = i >> 5, j = i & 31;
  double p = (double)pos[s];
  double inv = pow(10000.0, -(double)j / 32.0);
  double a = p * inv;
  cosT[i] = (float)cos(a);
  sinT[i] = (float)sin(a);
}

// ---------------- bt-GEMM: C[m,n] = sum_k A[m,k]*W[n,k] ----------------
// 128x128 tile, BK=32, 4 waves, global_load_lds staging (m97 structure).
// EPI: 0 = bf16 out, 1 = RoPE-fused bf16 out, 2 = f32 out
template<int EPI>
__global__ __launch_bounds__(256) void k_gemm_bt(
    const u16* __restrict__ A, const u16* __restrict__ W,
    void* __restrict__ Cout,
    const float* __restrict__ cosT, const float* __restrict__ sinT)
{
  __shared__ u16 Asl[128*32];
  __shared__ u16 Bsl[128*32];
  const int bm = blockIdx.x, bn = blockIdx.y;
  const int tid = threadIdx.x;
  const int wave = tid >> 6, lane = tid & 63;
  const int lg = lane >> 4, lr = lane & 15;
  const int wm = wave >> 1, wn = wave & 1;

  f32x4 acc[4][4];
#pragma unroll
  for (int i = 0; i < 4; ++i)
#pragma unroll
    for (int j = 0; j < 4; ++j) acc[i][j] = (f32x4){0,0,0,0};

  const int srow = lane >> 2;        // 0..15
  const int sk8  = (lane & 3) * 8;   // element offset within BK

  for (int kt = 0; kt < 32; ++kt) {
    const int k0 = kt * 32;
#pragma unroll
    for (int i = 0; i < 2; ++i) {
      const u16* ga = A + (size_t)(bm*128 + i*64 + wave*16 + srow)*DMODEL + k0 + sk8;
      const u16* gb = W + (size_t)(bn*128 + i*64 + wave*16 + srow)*DMODEL + k0 + sk8;
      async_copy16(ga, (char*)Asl + i*4096 + wave*1024);
      async_copy16(gb, (char*)Bsl + i*4096 + wave*1024);
    }
    __syncthreads();
    bf16x8 af[4], bfr[4];
#pragma unroll
    for (int mi = 0; mi < 4; ++mi)
      af[mi] = *(const bf16x8*)&Asl[(wm*64 + mi*16 + lr)*32 + lg*8];
#pragma unroll
    for (int ni = 0; ni < 4; ++ni)
      bfr[ni] = *(const bf16x8*)&Bsl[(wn*64 + ni*16 + lr)*32 + lg*8];
#pragma unroll
    for (int mi = 0; mi < 4; ++mi)
#pragma unroll
      for (int ni = 0; ni < 4; ++ni)
        acc[mi][ni] = __builtin_amdgcn_mfma_f32_16x16x32_bf16(af[mi], bfr[ni], acc[mi][ni], 0, 0, 0);
    __syncthreads();
  }

#pragma unroll
  for (int mi = 0; mi < 4; ++mi) {
    const int row0 = bm*128 + wm*64 + mi*16 + lg*4;
#pragma unroll
    for (int ni = 0; ni < 4; ++ni) {
      const int col = bn*128 + wn*64 + ni*16 + lr;
      f32x4 a = acc[mi][ni];
      if constexpr (EPI == 2) {
        float* C = (float*)Cout;
#pragma unroll
        for (int r = 0; r < 4; ++r) C[(size_t)(row0+r)*DMODEL + col] = a[r];
      } else if constexpr (EPI == 0) {
        u16* C = (u16*)Cout;
#pragma unroll
        for (int r = 0; r < 4; ++r) C[(size_t)(row0+r)*DMODEL + col] = f2bf(a[r]);
      } else {
        u16* C = (u16*)Cout;
        const int dd = col & 63;
        const int j = dd >> 1;
        const float sgn = (dd & 1) ? 1.0f : -1.0f;
#pragma unroll
        for (int r = 0; r < 4; ++r) {
          const int s = (row0 + r) & (SEQ-1);
          float v = a[r];
          float pv = __shfl_xor(v, 1, 64);   // partner within rotation pair
          float c = cosT[s*32 + j], sn = sinT[s*32 + j];
          // even d: v*cos - partner*sin ; odd d: partner*sin... -> v*cos + sgn*pv*sin
          C[(size_t)(row0+r)*DMODEL + col] = f2bf(v*c + sgn*pv*sn);
        }
      }
    }
  }
}

// ---------------- V transpose: (b,s,h,d) -> (b,h,d,s) ----------------
__global__ __launch_bounds__(256) void k_transpose_v(const u16* __restrict__ Vtmp,
                                                     u16* __restrict__ Vt) {
  const int st = blockIdx.x;   // 0..31 s-tiles of 64
  const int bh = blockIdx.y;   // 0..63
  const int b = bh >> 4, h = bh & 15;
  __shared__ u16 T[64*72];
  const int t = threadIdx.x;
#pragma unroll
  for (int ph = 0; ph < 2; ++ph) {
    int c = ph*256 + t;
    int sl = c >> 3, d8 = (c & 7) * 8;
    u16x8 v = *(const u16x8*)&Vtmp[(size_t)(b*SEQ + st*64 + sl)*DMODEL + h*64 + d8];
    *(u16x8*)&T[sl*72 + d8] = v;
  }
  __syncthreads();
#pragma unroll
  for (int ph = 0; ph < 2; ++ph) {
    int c = ph*256 + t;
    int dl = c >> 3, s8 = (c & 7) * 8;
    u16x8 v;
#pragma unroll
    for (int jj = 0; jj < 8; ++jj) v[jj] = T[(s8+jj)*72 + dl];
    *(u16x8*)&Vt[(size_t)(bh*64 + dl)*SEQ + st*64 + s8] = v;
  }
}

// ---------------- causal flash attention ----------------
// grid: (32 q-tiles of 64, 64 bh); 4 waves, wave = 16 q rows; KV tile = 64.
__global__ __launch_bounds__(256) void k_attn(
    const u16* __restrict__ Q, const u16* __restrict__ K,
    const u16* __restrict__ Vt, u16* __restrict__ O)
{
  const int qt = blockIdx.x;
  const int bh = blockIdx.y;
  const int b = bh >> 4, h = bh & 15;
  const int wave = threadIdx.x >> 6, lane = threadIdx.x & 63;
  const int lg = lane >> 4, lr = lane & 15;
  const int qrow = qt*64 + wave*16;

  __shared__ u16 Pl[4][16*72];
  u16* Pw = (u16*)Pl[wave];

  const u16* Qb = Q + (size_t)(b*SEQ)*DMODEL + h*64;
  const u16* Kb = K + (size_t)(b*SEQ)*DMODEL + h*64;
  const u16* Vb = Vt + (size_t)(bh*64)*SEQ;

  bf16x8 qf0 = *(const bf16x8*)(Qb + (size_t)(qrow + lr)*DMODEL + lg*8);
  bf16x8 qf1 = *(const bf16x8*)(Qb + (size_t)(qrow + lr)*DMODEL + 32 + lg*8);

  f32x4 o[4];
#pragma unroll
  for (int i = 0; i < 4; ++i) o[i] = (f32x4){0,0,0,0};
  float m_run[4] = {-INFINITY,-INFINITY,-INFINITY,-INFINITY};
  float l_run[4] = {0.f,0.f,0.f,0.f};

  for (int kt = 0; kt <= qt; ++kt) {
    const int k0 = kt*64;
    f32x4 sc[4];
#pragma unroll
    for (int nt = 0; nt < 4; ++nt) {
      const u16* Kp = Kb + (size_t)(k0 + nt*16 + lr)*DMODEL + lg*8;
      bf16x8 kf0 = *(const bf16x8*)Kp;
      bf16x8 kf1 = *(const bf16x8*)(Kp + 32);
      f32x4 z = (f32x4){0,0,0,0};
      z = __builtin_amdgcn_mfma_f32_16x16x32_bf16(qf0, kf0, z, 0, 0, 0);
      z = __builtin_amdgcn_mfma_f32_16x16x32_bf16(qf1, kf1, z, 0, 0, 0);
      sc[nt] = z;
    }
    if (kt == qt) {   // diagonal tile: mask + scale
#pragma unroll
      for (int nt = 0; nt < 4; ++nt) {
        const int col = k0 + nt*16 + lr;
#pragma unroll
        for (int r = 0; r < 4; ++r) {
          const int row = qrow + lg*4 + r;
          sc[nt][r] = (col <= row) ? sc[nt][r]*0.125f : -INFINITY;
        }
      }
    } else {
#pragma unroll
      for (int nt = 0; nt < 4; ++nt)
#pragma unroll
        for (int r = 0; r < 4; ++r) sc[nt][r] *= 0.125f;
    }
    // wave-parallel row max (16 lanes share the 4 rows of a group)
    float mt[4];
#pragma unroll
    for (int r = 0; r < 4; ++r)
      mt[r] = fmaxf(fmaxf(sc[0][r], sc[1][r]), fmaxf(sc[2][r], sc[3][r]));
#pragma unroll
    for (int off = 1; off < 16; off <<= 1)
#pragma unroll
      for (int r = 0; r < 4; ++r) mt[r] = fmaxf(mt[r], __shfl_xor(mt[r], off, 64));
    float alpha[4];
#pragma unroll
    for (int r = 0; r < 4; ++r) {
      float mn = fmaxf(m_run[r], mt[r]);
      alpha[r] = __expf(m_run[r] - mn);
      m_run[r] = mn;
    }
    float ps[4] = {0.f,0.f,0.f,0.f};
#pragma unroll
    for (int nt = 0; nt < 4; ++nt)
#pragma unroll
      for (int r = 0; r < 4; ++r) {
        float p = __expf(sc[nt][r] - m_run[r]);
        ps[r] += p;
        Pw[(lg*4 + r)*72 + nt*16 + lr] = f2bf(p);
      }
#pragma unroll
    for (int off = 1; off < 16; off <<= 1)
#pragma unroll
      for (int r = 0; r < 4; ++r) ps[r] += __shfl_xor(ps[r], off, 64);
#pragma unroll
    for (int r = 0; r < 4; ++r) l_run[r] = l_run[r]*alpha[r] + ps[r];
#pragma unroll
    for (int dt = 0; dt < 4; ++dt)
#pragma unroll
      for (int r = 0; r < 4; ++r) o[dt][r] *= alpha[r];
    // PV: P via per-wave LDS (stride 72 -> ~2-way banks), V from (b,h,d,s)
    bf16x8 pf0 = *(const bf16x8*)&Pw[lr*72 + lg*8];
    bf16x8 pf1 = *(const bf16x8*)&Pw[lr*72 + 32 + lg*8];
#pragma unroll
    for (int dt = 0; dt < 4; ++dt) {
      const u16* Vp = Vb + (size_t)(dt*16 + lr)*SEQ + k0 + lg*8;
      bf16x8 v0 = *(const bf16x8*)Vp;
      bf16x8 v1 = *(const bf16x8*)(Vp + 32);
      o[dt] = __builtin_amdgcn_mfma_f32_16x16x32_bf16(pf0, v0, o[dt], 0, 0, 0);
      o[dt] = __builtin_amdgcn_mfma_f32_16x16x32_bf16(pf1, v1, o[dt], 0, 0, 0);
    }
  }
#pragma unroll
  for (int dt = 0; dt < 4; ++dt)
#pragma unroll
    for (int r = 0; r < 4; ++r) {
      const int row = qrow + lg*4 + r;
      O[(size_t)(b*SEQ + row)*DMODEL + h*64 + dt*16 + lr] = f2bf(o[dt][r] / l_run[r]);
    }
}

// ---------------- launch ----------------
extern "C" void kernel_launch(void* const* d_in, const int* in_sizes, int n_in,
                              void* d_out, int out_size, void* d_ws, size_t ws_size,
                              hipStream_t stream) {
  const float* x  = (const float*)d_in[0];
  const float* Wq = (const float*)d_in[1];
  const float* Wk = (const float*)d_in[2];
  const float* Wv = (const float*)d_in[3];
  const float* Wo = (const float*)d_in[4];
  const int* pos  = (const int*)d_in[5];
  float* out = (float*)d_out;

  // workspace layout (bytes)
  const size_t SZ_X   = (size_t)MROWS*DMODEL*2;   // 16 MiB
  const size_t SZ_W   = (size_t)DMODEL*DMODEL*2;  // 2 MiB
  const size_t SZ_TAB = (size_t)SEQ*32*4;         // 256 KiB
  char* w = (char*)d_ws;
  u16* xb   = (u16*)(w);
  u16* Wqb  = (u16*)(w + SZ_X);
  u16* Wkb  = (u16*)(w + SZ_X + SZ_W);
  u16* Wvb  = (u16*)(w + SZ_X + 2*SZ_W);
  u16* Wob  = (u16*)(w + SZ_X + 3*SZ_W);
  float* cosT = (float*)(w + SZ_X + 4*SZ_W);
  float* sinT = (float*)(w + SZ_X + 4*SZ_W + SZ_TAB);
  u16* Qb   = (u16*)(w + SZ_X + 4*SZ_W + 2*SZ_TAB);
  u16* Kb   = (u16*)(w + 2*SZ_X + 4*SZ_W + 2*SZ_TAB);
  u16* Vtmp = (u16*)(w + 3*SZ_X + 4*SZ_W + 2*SZ_TAB);   // reused as O after transpose
  u16* Vt   = (u16*)(w + 4*SZ_X + 4*SZ_W + 2*SZ_TAB);
  const size_t need = 5*SZ_X + 4*SZ_W + 2*SZ_TAB;
  if (ws_size < need) return;  // will fail validation visibly

  // convert inputs to bf16
  k_cvt<<<(MROWS*DMODEL/4 + 255)/256, 256, 0, stream>>>(x, xb, MROWS*DMODEL/4);
  k_cvt<<<(DMODEL*DMODEL/4 + 255)/256, 256, 0, stream>>>(Wq, Wqb, DMODEL*DMODEL/4);
  k_cvt<<<(DMODEL*DMODEL/4 + 255)/256, 256, 0, stream>>>(Wk, Wkb, DMODEL*DMODEL/4);
  k_cvt<<<(DMODEL*DMODEL/4 + 255)/256, 256, 0, stream>>>(Wv, Wvb, DMODEL*DMODEL/4);
  k_cvt<<<(DMODEL*DMODEL/4 + 255)/256, 256, 0, stream>>>(Wo, Wob, DMODEL*DMODEL/4);
  k_rope_tab<<<SEQ*32/256, 256, 0, stream>>>(pos, cosT, sinT);

  dim3 gproj(MROWS/128, DMODEL/128);
  k_gemm_bt<1><<<gproj, 256, 0, stream>>>(xb, Wqb, Qb, cosT, sinT);
  k_gemm_bt<1><<<gproj, 256, 0, stream>>>(xb, Wkb, Kb, cosT, sinT);
  k_gemm_bt<0><<<gproj, 256, 0, stream>>>(xb, Wvb, Vtmp, cosT, sinT);
  k_transpose_v<<<dim3(SEQ/64, BATCH*NHEADS), 256, 0, stream>>>(Vtmp, Vt);
  k_attn<<<dim3(SEQ/64, BATCH*NHEADS), 256, 0, stream>>>(Qb, Kb, Vt, Vtmp /*O*/);
  k_gemm_bt<2><<<gproj, 256, 0, stream>>>(Vtmp /*O*/, Wob, out, cosT, sinT);
}

// Round 2
// 353.278 us; speedup vs baseline: 1.8058x; 1.8058x over previous
//
#include <hip/hip_runtime.h>
#include <hip/hip_bf16.h>
#include <math.h>

#define SEQ 2048
#define BATCH 4
#define MROWS (BATCH*SEQ)     // 8192
#define DMODEL 1024
#define NHEADS 16
#define DKH 64

typedef float f32x4 __attribute__((ext_vector_type(4)));
typedef __bf16 bf16x8 __attribute__((ext_vector_type(8)));
typedef unsigned short u16;
typedef u16 u16x4 __attribute__((ext_vector_type(4)));
typedef u16 u16x8 __attribute__((ext_vector_type(8)));

__device__ __forceinline__ u16 f2bf(float f) {
  union { float f; unsigned u; } v; v.f = f;
  unsigned r = v.u + 0x7FFFu + ((v.u >> 16) & 1u);
  return (u16)(r >> 16);
}

__device__ __forceinline__ void async_copy16(const void* g, void* l) {
  __builtin_amdgcn_global_load_lds(
      (const __attribute__((address_space(1))) void*)g,
      (__attribute__((address_space(3))) void*)l, 16, 0, 0);
}

// ---------------- f32 -> bf16 convert (vectorized) ----------------
__global__ __launch_bounds__(256) void k_cvt(const float* __restrict__ in,
                                             u16* __restrict__ out, int n4) {
  int i = blockIdx.x * 256 + threadIdx.x;
  if (i >= n4) return;
  float4 v = ((const float4*)in)[i];
  u16x4 o;
  o[0] = f2bf(v.x); o[1] = f2bf(v.y); o[2] = f2bf(v.z); o[3] = f2bf(v.w);
  ((u16x4*)out)[i] = o;
}

// ---------------- RoPE tables: cos/sin[s][j], j in [0,32) ----------------
__global__ __launch_bounds__(256) void k_rope_tab(const int* __restrict__ pos,
                                                  float* __restrict__ cosT,
                                                  float* __restrict__ sinT) {
  int i = blockIdx.x * 256 + threadIdx.x;   // SEQ*32 = 65536 total
  int s = i >> 5, j = i & 31;
  double p = (double)pos[s];
  double inv = pow(10000.0, -(double)j / 32.0);
  double a = p * inv;
  cosT[i] = (float)cos(a);
  sinT[i] = (float)sin(a);
}

// ---------------- bt-GEMM: C[m,n] = sum_k A[m,k]*W[n,k] ----------------
// 128x128 tile, BK=32, 4 waves, global_load_lds staging (m97 structure).
// EPI: 0 = bf16 out, 1 = RoPE-fused bf16 out, 2 = f32 out
template<int EPI>
__global__ __launch_bounds__(256) void k_gemm_bt(
    const u16* __restrict__ A, const u16* __restrict__ W,
    void* __restrict__ Cout,
    const float* __restrict__ cosT, const float* __restrict__ sinT)
{
  __shared__ u16 Asl[128*32];
  __shared__ u16 Bsl[128*32];
  const int bm = blockIdx.x, bn = blockIdx.y;
  const int tid = threadIdx.x;
  const int wave = tid >> 6, lane = tid & 63;
  const int lg = lane >> 4, lr = lane & 15;
  const int wm = wave >> 1, wn = wave & 1;

  f32x4 acc[4][4];
#pragma unroll
  for (int i = 0; i < 4; ++i)
#pragma unroll
    for (int j = 0; j < 4; ++j) acc[i][j] = (f32x4){0,0,0,0};

  const int srow = lane >> 2;        // 0..15
  const int sk8  = (lane & 3) * 8;   // element offset within BK

  for (int kt = 0; kt < 32; ++kt) {
    const int k0 = kt * 32;
#pragma unroll
    for (int i = 0; i < 2; ++i) {
      const u16* ga = A + (size_t)(bm*128 + i*64 + wave*16 + srow)*DMODEL + k0 + sk8;
      const u16* gb = W + (size_t)(bn*128 + i*64 + wave*16 + srow)*DMODEL + k0 + sk8;
      async_copy16(ga, (char*)Asl + i*4096 + wave*1024);
      async_copy16(gb, (char*)Bsl + i*4096 + wave*1024);
    }
    __syncthreads();
    bf16x8 af[4], bfr[4];
#pragma unroll
    for (int mi = 0; mi < 4; ++mi)
      af[mi] = *(const bf16x8*)&Asl[(wm*64 + mi*16 + lr)*32 + lg*8];
#pragma unroll
    for (int ni = 0; ni < 4; ++ni)
      bfr[ni] = *(const bf16x8*)&Bsl[(wn*64 + ni*16 + lr)*32 + lg*8];
#pragma unroll
    for (int mi = 0; mi < 4; ++mi)
#pragma unroll
      for (int ni = 0; ni < 4; ++ni)
        acc[mi][ni] = __builtin_amdgcn_mfma_f32_16x16x32_bf16(af[mi], bfr[ni], acc[mi][ni], 0, 0, 0);
    __syncthreads();
  }

#pragma unroll
  for (int mi = 0; mi < 4; ++mi) {
    const int row0 = bm*128 + wm*64 + mi*16 + lg*4;
#pragma unroll
    for (int ni = 0; ni < 4; ++ni) {
      const int col = bn*128 + wn*64 + ni*16 + lr;
      f32x4 a = acc[mi][ni];
      if constexpr (EPI == 2) {
        float* C = (float*)Cout;
#pragma unroll
        for (int r = 0; r < 4; ++r) C[(size_t)(row0+r)*DMODEL + col] = a[r];
      } else if constexpr (EPI == 0) {
        u16* C = (u16*)Cout;
#pragma unroll
        for (int r = 0; r < 4; ++r) C[(size_t)(row0+r)*DMODEL + col] = f2bf(a[r]);
      } else {
        u16* C = (u16*)Cout;
        const int dd = col & 63;
        const int j = dd >> 1;
        const float sgn = (dd & 1) ? 1.0f : -1.0f;
#pragma unroll
        for (int r = 0; r < 4; ++r) {
          const int s = (row0 + r) & (SEQ-1);
          float v = a[r];
          float pv = __shfl_xor(v, 1, 64);   // partner within rotation pair
          float c = cosT[s*32 + j], sn = sinT[s*32 + j];
          C[(size_t)(row0+r)*DMODEL + col] = f2bf(v*c + sgn*pv*sn);
        }
      }
    }
  }
}

// ---------------- V transpose: (b,s,h,d) -> (b,h,d,s) ----------------
__global__ __launch_bounds__(256) void k_transpose_v(const u16* __restrict__ Vtmp,
                                                     u16* __restrict__ Vt) {
  const int st = blockIdx.x;   // 0..31 s-tiles of 64
  const int bh = blockIdx.y;   // 0..63
  const int b = bh >> 4, h = bh & 15;
  __shared__ u16 T[64*72];
  const int t = threadIdx.x;
#pragma unroll
  for (int ph = 0; ph < 2; ++ph) {
    int c = ph*256 + t;
    int sl = c >> 3, d8 = (c & 7) * 8;
    u16x8 v = *(const u16x8*)&Vtmp[(size_t)(b*SEQ + st*64 + sl)*DMODEL + h*64 + d8];
    *(u16x8*)&T[sl*72 + d8] = v;
  }
  __syncthreads();
#pragma unroll
  for (int ph = 0; ph < 2; ++ph) {
    int c = ph*256 + t;
    int dl = c >> 3, s8 = (c & 7) * 8;
    u16x8 v;
#pragma unroll
    for (int jj = 0; jj < 8; ++jj) v[jj] = T[(s8+jj)*72 + dl];
    *(u16x8*)&Vt[(size_t)(bh*64 + dl)*SEQ + st*64 + s8] = v;
  }
}

// ---------------- causal flash attention v2 ----------------
// grid: (16 q-tiles of 128, 64 bh); 4 waves x 32 q-rows; KV tile = 64.
// K/V staged in LDS (XOR-swizzled via pre-swizzled global src), double-buffered.
__global__ __launch_bounds__(256) void k_attn(
    const u16* __restrict__ Q, const u16* __restrict__ K,
    const u16* __restrict__ Vt, u16* __restrict__ O)
{
  const int qt = (gridDim.x - 1) - blockIdx.x;   // LPT: longest blocks first
  const int bh = blockIdx.y;
  const int b = bh >> 4, h = bh & 15;
  const int wave = threadIdx.x >> 6, lane = threadIdx.x & 63;
  const int lg = lane >> 4, lr = lane & 15;
  const int R0 = qt*128 + wave*32;               // wave's first q row

  __shared__ alignas(16) u16 Ks[2][64*64];
  __shared__ alignas(16) u16 Vs[2][64*64];
  __shared__ alignas(16) u16 Pl[4][2][16*72];

  const u16* Qb = Q + (size_t)(b*SEQ)*DMODEL + h*64;
  const u16* Kb = K + (size_t)(b*SEQ)*DMODEL + h*64;
  const u16* Vb = Vt + (size_t)(bh*64)*SEQ;

  // Q fragments: 2 row-frags x 2 k-chunks
  bf16x8 qf[2][2];
#pragma unroll
  for (int m = 0; m < 2; ++m) {
    const u16* Qp = Qb + (size_t)(R0 + m*16 + lr)*DMODEL + lg*8;
    qf[m][0] = *(const bf16x8*)Qp;
    qf[m][1] = *(const bf16x8*)(Qp + 32);
  }

  f32x4 o[2][4];
#pragma unroll
  for (int m = 0; m < 2; ++m)
#pragma unroll
    for (int i = 0; i < 4; ++i) o[m][i] = (f32x4){0,0,0,0};
  float m_run[2][4], l_run[2][4];
#pragma unroll
  for (int m = 0; m < 2; ++m)
#pragma unroll
    for (int r = 0; r < 4; ++r) { m_run[m][r] = -INFINITY; l_run[m][r] = 0.f; }

  const int KT = 2*qt + 2;

  // staging: 512 16B-chunks per tile pair-half; chunk idx -> (row, ch), src col
  // pre-swizzled: LDS[row][c] = global[row][c ^ (row&7)]  (rule #21 compliant)
  auto stage = [&](int buf, int kt) {
    const int k0 = kt*64;
#pragma unroll
    for (int i = 0; i < 2; ++i) {
      const int idx = wave*128 + i*64 + lane;
      const int row = idx >> 3, ch = idx & 7;
      const int sch = (ch ^ (row & 7)) * 8;
      async_copy16(Kb + (size_t)(k0 + row)*DMODEL + sch,
                   (char*)Ks[buf] + (wave*128 + i*64)*16);
      async_copy16(Vb + (size_t)row*SEQ + k0 + sch,
                   (char*)Vs[buf] + (wave*128 + i*64)*16);
    }
  };

  stage(0, 0);
  __syncthreads();

  for (int kt = 0; kt < KT; ++kt) {
    const int cur = kt & 1;
    if (kt + 1 < KT) stage(cur ^ 1, kt + 1);   // issue next-tile loads early

    const int k0 = kt*64;
    if (k0 <= R0 + 31) {                        // not fully masked for this wave
      const u16* Kw = Ks[cur];
      const u16* Vw = Vs[cur];
      const int sw = lr & 7;                    // swizzle key (row&7 == lr&7)

      f32x4 sc[2][4];
#pragma unroll
      for (int nt = 0; nt < 4; ++nt) {
        const int c0 = (lg ^ sw) * 8;
        const int c1 = ((lg + 4) ^ sw) * 8;
        bf16x8 kf0 = *(const bf16x8*)&Kw[(nt*16 + lr)*64 + c0];
        bf16x8 kf1 = *(const bf16x8*)&Kw[(nt*16 + lr)*64 + c1];
#pragma unroll
        for (int m = 0; m < 2; ++m) {
          f32x4 z = (f32x4){0,0,0,0};
          z = __builtin_amdgcn_mfma_f32_16x16x32_bf16(qf[m][0], kf0, z, 0, 0, 0);
          z = __builtin_amdgcn_mfma_f32_16x16x32_bf16(qf[m][1], kf1, z, 0, 0, 0);
          sc[m][nt] = z;
        }
      }
      const bool partial = (k0 + 63 > R0);
      if (partial) {
#pragma unroll
        for (int m = 0; m < 2; ++m)
#pragma unroll
          for (int nt = 0; nt < 4; ++nt) {
            const int col = k0 + nt*16 + lr;
#pragma unroll
            for (int r = 0; r < 4; ++r) {
              const int row = R0 + m*16 + lg*4 + r;
              sc[m][nt][r] = (col <= row) ? sc[m][nt][r]*0.125f : -INFINITY;
            }
          }
      } else {
#pragma unroll
        for (int m = 0; m < 2; ++m)
#pragma unroll
          for (int nt = 0; nt < 4; ++nt)
#pragma unroll
            for (int r = 0; r < 4; ++r) sc[m][nt][r] *= 0.125f;
      }

#pragma unroll
      for (int m = 0; m < 2; ++m) {
        u16* Pw = Pl[wave][m];
        float mt[4];
#pragma unroll
        for (int r = 0; r < 4; ++r)
          mt[r] = fmaxf(fmaxf(sc[m][0][r], sc[m][1][r]),
                        fmaxf(sc[m][2][r], sc[m][3][r]));
#pragma unroll
        for (int off = 1; off < 16; off <<= 1)
#pragma unroll
          for (int r = 0; r < 4; ++r) mt[r] = fmaxf(mt[r], __shfl_xor(mt[r], off, 64));
        float alpha[4];
#pragma unroll
        for (int r = 0; r < 4; ++r) {
          float mn = fmaxf(m_run[m][r], mt[r]);
          alpha[r] = __expf(m_run[m][r] - mn);
          m_run[m][r] = mn;
        }
        float ps[4] = {0.f,0.f,0.f,0.f};
#pragma unroll
        for (int nt = 0; nt < 4; ++nt)
#pragma unroll
          for (int r = 0; r < 4; ++r) {
            float p = __expf(sc[m][nt][r] - m_run[m][r]);
            ps[r] += p;
            Pw[(lg*4 + r)*72 + nt*16 + lr] = f2bf(p);
          }
#pragma unroll
        for (int off = 1; off < 16; off <<= 1)
#pragma unroll
          for (int r = 0; r < 4; ++r) ps[r] += __shfl_xor(ps[r], off, 64);
#pragma unroll
        for (int r = 0; r < 4; ++r) l_run[m][r] = l_run[m][r]*alpha[r] + ps[r];
#pragma unroll
        for (int dt = 0; dt < 4; ++dt)
#pragma unroll
          for (int r = 0; r < 4; ++r) o[m][dt][r] *= alpha[r];
      }

      // PV: P via per-wave LDS, V from swizzled LDS tile (d-major)
      bf16x8 pf[2][2];
#pragma unroll
      for (int m = 0; m < 2; ++m) {
        pf[m][0] = *(const bf16x8*)&Pl[wave][m][lr*72 + lg*8];
        pf[m][1] = *(const bf16x8*)&Pl[wave][m][lr*72 + 32 + lg*8];
      }
#pragma unroll
      for (int dt = 0; dt < 4; ++dt) {
        const int c0 = (lg ^ sw) * 8;
        const int c1 = ((lg + 4) ^ sw) * 8;
        bf16x8 v0 = *(const bf16x8*)&Vw[(dt*16 + lr)*64 + c0];
        bf16x8 v1 = *(const bf16x8*)&Vw[(dt*16 + lr)*64 + c1];
#pragma unroll
        for (int m = 0; m < 2; ++m) {
          o[m][dt] = __builtin_amdgcn_mfma_f32_16x16x32_bf16(pf[m][0], v0, o[m][dt], 0, 0, 0);
          o[m][dt] = __builtin_amdgcn_mfma_f32_16x16x32_bf16(pf[m][1], v1, o[m][dt], 0, 0, 0);
        }
      }
    }
    __syncthreads();   // drains vmcnt(0): next tile staged, this tile's reads done
  }

#pragma unroll
  for (int m = 0; m < 2; ++m)
#pragma unroll
    for (int r = 0; r < 4; ++r) {
      const float inv = 1.0f / l_run[m][r];
      const int row = R0 + m*16 + lg*4 + r;
#pragma unroll
      for (int dt = 0; dt < 4; ++dt)
        O[(size_t)(b*SEQ + row)*DMODEL + h*64 + dt*16 + lr] = f2bf(o[m][dt][r] * inv);
    }
}

// ---------------- launch ----------------
extern "C" void kernel_launch(void* const* d_in, const int* in_sizes, int n_in,
                              void* d_out, int out_size, void* d_ws, size_t ws_size,
                              hipStream_t stream) {
  const float* x  = (const float*)d_in[0];
  const float* Wq = (const float*)d_in[1];
  const float* Wk = (const float*)d_in[2];
  const float* Wv = (const float*)d_in[3];
  const float* Wo = (const float*)d_in[4];
  const int* pos  = (const int*)d_in[5];
  float* out = (float*)d_out;

  // workspace layout (bytes)
  const size_t SZ_X   = (size_t)MROWS*DMODEL*2;   // 16 MiB
  const size_t SZ_W   = (size_t)DMODEL*DMODEL*2;  // 2 MiB
  const size_t SZ_TAB = (size_t)SEQ*32*4;         // 256 KiB
  char* w = (char*)d_ws;
  u16* xb   = (u16*)(w);
  u16* Wqb  = (u16*)(w + SZ_X);
  u16* Wkb  = (u16*)(w + SZ_X + SZ_W);
  u16* Wvb  = (u16*)(w + SZ_X + 2*SZ_W);
  u16* Wob  = (u16*)(w + SZ_X + 3*SZ_W);
  float* cosT = (float*)(w + SZ_X + 4*SZ_W);
  float* sinT = (float*)(w + SZ_X + 4*SZ_W + SZ_TAB);
  u16* Qb   = (u16*)(w + SZ_X + 4*SZ_W + 2*SZ_TAB);
  u16* Kb   = (u16*)(w + 2*SZ_X + 4*SZ_W + 2*SZ_TAB);
  u16* Vtmp = (u16*)(w + 3*SZ_X + 4*SZ_W + 2*SZ_TAB);   // reused as O after transpose
  u16* Vt   = (u16*)(w + 4*SZ_X + 4*SZ_W + 2*SZ_TAB);
  const size_t need = 5*SZ_X + 4*SZ_W + 2*SZ_TAB;
  if (ws_size < need) return;

  // convert inputs to bf16
  k_cvt<<<(MROWS*DMODEL/4 + 255)/256, 256, 0, stream>>>(x, xb, MROWS*DMODEL/4);
  k_cvt<<<(DMODEL*DMODEL/4 + 255)/256, 256, 0, stream>>>(Wq, Wqb, DMODEL*DMODEL/4);
  k_cvt<<<(DMODEL*DMODEL/4 + 255)/256, 256, 0, stream>>>(Wk, Wkb, DMODEL*DMODEL/4);
  k_cvt<<<(DMODEL*DMODEL/4 + 255)/256, 256, 0, stream>>>(Wv, Wvb, DMODEL*DMODEL/4);
  k_cvt<<<(DMODEL*DMODEL/4 + 255)/256, 256, 0, stream>>>(Wo, Wob, DMODEL*DMODEL/4);
  k_rope_tab<<<SEQ*32/256, 256, 0, stream>>>(pos, cosT, sinT);

  dim3 gproj(MROWS/128, DMODEL/128);
  k_gemm_bt<1><<<gproj, 256, 0, stream>>>(xb, Wqb, Qb, cosT, sinT);
  k_gemm_bt<1><<<gproj, 256, 0, stream>>>(xb, Wkb, Kb, cosT, sinT);
  k_gemm_bt<0><<<gproj, 256, 0, stream>>>(xb, Wvb, Vtmp, cosT, sinT);
  k_transpose_v<<<dim3(SEQ/64, BATCH*NHEADS), 256, 0, stream>>>(Vtmp, Vt);
  k_attn<<<dim3(16, BATCH*NHEADS), 256, 0, stream>>>(Qb, Kb, Vt, Vtmp /*O*/);
  k_gemm_bt<2><<<gproj, 256, 0, stream>>>(Vtmp /*O*/, Wob, out, cosT, sinT);
}

// Round 5
// 227.301 us; speedup vs baseline: 2.8067x; 1.5542x over previous
//
#include <hip/hip_runtime.h>
#include <hip/hip_bf16.h>
#include <math.h>

#define SEQ 2048
#define BATCH 4
#define MROWS (BATCH*SEQ)     // 8192
#define DMODEL 1024
#define NHEADS 16
#define DKH 64

typedef float f32x4 __attribute__((ext_vector_type(4)));
typedef float f32x16 __attribute__((ext_vector_type(16)));
typedef __bf16 bf16x8 __attribute__((ext_vector_type(8)));
typedef unsigned short u16;
typedef unsigned int u32;
typedef u16 u16x4 __attribute__((ext_vector_type(4)));
typedef u16 u16x8 __attribute__((ext_vector_type(8)));
typedef u32 u32x4v __attribute__((ext_vector_type(4)));

__device__ __forceinline__ u16 f2bf(float f) {
  union { float f; unsigned u; } v; v.f = f;
  unsigned r = v.u + 0x7FFFu + ((v.u >> 16) & 1u);
  return (u16)(r >> 16);
}

__device__ __forceinline__ void async_copy16(const void* g, void* l) {
  __builtin_amdgcn_global_load_lds(
      (const __attribute__((address_space(1))) void*)g,
      (__attribute__((address_space(3))) void*)l, 16, 0, 0);
}

__device__ __forceinline__ u32 cvtpk(float lo, float hi) {
  u32 r;
  asm("v_cvt_pk_bf16_f32 %0, %1, %2" : "=v"(r) : "v"(lo), "v"(hi));
  return r;
}

// ---------------- f32 -> bf16 convert (vectorized) ----------------
__global__ __launch_bounds__(256) void k_cvt(const float* __restrict__ in,
                                             u16* __restrict__ out, int n4) {
  int i = blockIdx.x * 256 + threadIdx.x;
  if (i >= n4) return;
  float4 v = ((const float4*)in)[i];
  u16x4 o;
  o[0] = f2bf(v.x); o[1] = f2bf(v.y); o[2] = f2bf(v.z); o[3] = f2bf(v.w);
  ((u16x4*)out)[i] = o;
}

// ---------------- RoPE tables: cos/sin[s][j], j in [0,32) ----------------
__global__ __launch_bounds__(256) void k_rope_tab(const int* __restrict__ pos,
                                                  float* __restrict__ cosT,
                                                  float* __restrict__ sinT) {
  int i = blockIdx.x * 256 + threadIdx.x;   // SEQ*32 = 65536 total
  int s = i >> 5, j = i & 31;
  double p = (double)pos[s];
  double inv = pow(10000.0, -(double)j / 32.0);
  double a = p * inv;
  cosT[i] = (float)cos(a);
  sinT[i] = (float)sin(a);
}

// ---------------- bt-GEMM: C[m,n] = sum_k A[m,k]*W[n,k] ----------------
template<int EPI>
__global__ __launch_bounds__(256) void k_gemm_bt(
    const u16* __restrict__ A, const u16* __restrict__ W,
    void* __restrict__ Cout,
    const float* __restrict__ cosT, const float* __restrict__ sinT)
{
  __shared__ u16 Asl[128*32];
  __shared__ u16 Bsl[128*32];
  const int bm = blockIdx.x, bn = blockIdx.y;
  const int tid = threadIdx.x;
  const int wave = tid >> 6, lane = tid & 63;
  const int lg = lane >> 4, lr = lane & 15;
  const int wm = wave >> 1, wn = wave & 1;

  f32x4 acc[4][4];
#pragma unroll
  for (int i = 0; i < 4; ++i)
#pragma unroll
    for (int j = 0; j < 4; ++j) acc[i][j] = (f32x4){0,0,0,0};

  const int srow = lane >> 2;
  const int sk8  = (lane & 3) * 8;

  for (int kt = 0; kt < 32; ++kt) {
    const int k0 = kt * 32;
#pragma unroll
    for (int i = 0; i < 2; ++i) {
      const u16* ga = A + (size_t)(bm*128 + i*64 + wave*16 + srow)*DMODEL + k0 + sk8;
      const u16* gb = W + (size_t)(bn*128 + i*64 + wave*16 + srow)*DMODEL + k0 + sk8;
      async_copy16(ga, (char*)Asl + i*4096 + wave*1024);
      async_copy16(gb, (char*)Bsl + i*4096 + wave*1024);
    }
    __syncthreads();
    bf16x8 af[4], bfr[4];
#pragma unroll
    for (int mi = 0; mi < 4; ++mi)
      af[mi] = *(const bf16x8*)&Asl[(wm*64 + mi*16 + lr)*32 + lg*8];
#pragma unroll
    for (int ni = 0; ni < 4; ++ni)
      bfr[ni] = *(const bf16x8*)&Bsl[(wn*64 + ni*16 + lr)*32 + lg*8];
#pragma unroll
    for (int mi = 0; mi < 4; ++mi)
#pragma unroll
      for (int ni = 0; ni < 4; ++ni)
        acc[mi][ni] = __builtin_amdgcn_mfma_f32_16x16x32_bf16(af[mi], bfr[ni], acc[mi][ni], 0, 0, 0);
    __syncthreads();
  }

#pragma unroll
  for (int mi = 0; mi < 4; ++mi) {
    const int row0 = bm*128 + wm*64 + mi*16 + lg*4;
#pragma unroll
    for (int ni = 0; ni < 4; ++ni) {
      const int col = bn*128 + wn*64 + ni*16 + lr;
      f32x4 a = acc[mi][ni];
      if constexpr (EPI == 2) {
        float* C = (float*)Cout;
#pragma unroll
        for (int r = 0; r < 4; ++r) C[(size_t)(row0+r)*DMODEL + col] = a[r];
      } else if constexpr (EPI == 0) {
        u16* C = (u16*)Cout;
#pragma unroll
        for (int r = 0; r < 4; ++r) C[(size_t)(row0+r)*DMODEL + col] = f2bf(a[r]);
      } else {
        u16* C = (u16*)Cout;
        const int dd = col & 63;
        const int j = dd >> 1;
        const float sgn = (dd & 1) ? 1.0f : -1.0f;
#pragma unroll
        for (int r = 0; r < 4; ++r) {
          const int s = (row0 + r) & (SEQ-1);
          float v = a[r];
          float pv = __shfl_xor(v, 1, 64);
          float c = cosT[s*32 + j], sn = sinT[s*32 + j];
          C[(size_t)(row0+r)*DMODEL + col] = f2bf(v*c + sgn*pv*sn);
        }
      }
    }
  }
}

// ---------------- V transpose: (b,s,h,d) -> (b,h,d,s) ----------------
__global__ __launch_bounds__(256) void k_transpose_v(const u16* __restrict__ Vtmp,
                                                     u16* __restrict__ Vt) {
  const int st = blockIdx.x;
  const int bh = blockIdx.y;
  const int b = bh >> 4, h = bh & 15;
  __shared__ u16 T[64*72];
  const int t = threadIdx.x;
#pragma unroll
  for (int ph = 0; ph < 2; ++ph) {
    int c = ph*256 + t;
    int sl = c >> 3, d8 = (c & 7) * 8;
    u16x8 v = *(const u16x8*)&Vtmp[(size_t)(b*SEQ + st*64 + sl)*DMODEL + h*64 + d8];
    *(u16x8*)&T[sl*72 + d8] = v;
  }
  __syncthreads();
#pragma unroll
  for (int ph = 0; ph < 2; ++ph) {
    int c = ph*256 + t;
    int dl = c >> 3, s8 = (c & 7) * 8;
    u16x8 v;
#pragma unroll
    for (int jj = 0; jj < 8; ++jj) v[jj] = T[(s8+jj)*72 + dl];
    *(u16x8*)&Vt[(size_t)(bh*64 + dl)*SEQ + st*64 + s8] = v;
  }
}

// ---------------- causal flash attention v3b (swapped-QK, in-reg softmax) ---
// grid: (64 bh, 8 q-tiles of 256); 8 waves x 32 q-rows; KVBLK = 64.
// S^T = mfma_32x32x16(K, Q): lane holds P-row halves for q = lane&31;
// cross-lane 32-swaps via __shfl_xor (direction-assumption-free).
__global__ __launch_bounds__(512) void k_attn(
    const u16* __restrict__ Q, const u16* __restrict__ K,
    const u16* __restrict__ Vt, u16* __restrict__ O)
{
  const int bh = blockIdx.x;
  const int qt = (gridDim.y - 1) - blockIdx.y;   // LPT: heaviest q-tiles first
  const int b = bh >> 4, h = bh & 15;
  const int wave = threadIdx.x >> 6, lane = threadIdx.x & 63;
  const int ql = lane & 31, hi = lane >> 5, hi4 = hi * 4;
  const int R0 = qt*256 + wave*32;

  __shared__ alignas(16) u16 Ks[2][64*64];
  __shared__ alignas(16) u16 Vs[2][64*64];

  const u16* Qb = Q + (size_t)(b*SEQ)*DMODEL + h*64;
  const u16* Kb = K + (size_t)(b*SEQ)*DMODEL + h*64;
  const u16* Vb = Vt + (size_t)(bh*64)*SEQ;

  // Q as B-operand: lane holds Q[R0+ql][j*16 + hi*8 + i]
  bf16x8 qf[4];
#pragma unroll
  for (int j = 0; j < 4; ++j)
    qf[j] = *(const bf16x8*)(Qb + (size_t)(R0 + ql)*DMODEL + j*16 + hi*8);

  f32x16 o0 = (f32x16)(0.f), o1 = (f32x16)(0.f);   // O^T accum, d-tiles 0,1
  float m_run = -INFINITY, l_run = 0.f;
  const float SCL = 0.18033688f;    // 0.125 * log2(e)
  const float THR2 = 11.5415603f;   // 8 * log2(e)

  const int KT = (qt + 1) * 4;

  // stage one KV tile: 512 threads x (1 K-chunk + 1 V-chunk of 16B)
  // pre-swizzled source (rule #21): LDS[row][c] = global[row][c ^ (row&7)]
  auto stage = [&](int buf, int kt) {
    const int idx = threadIdx.x;            // 0..511
    const int row = idx >> 3, ch = idx & 7;
    const int sch = (ch ^ (row & 7)) * 8;
    const int k0 = kt * 64;
    async_copy16(Kb + (size_t)(k0 + row)*DMODEL + sch, (char*)Ks[buf] + idx*16);
    async_copy16(Vb + (size_t)row*SEQ + k0 + sch,      (char*)Vs[buf] + idx*16);
  };

  stage(0, 0);
  __syncthreads();

  for (int kt = 0; kt < KT; ++kt) {
    const int cur = kt & 1;
    if (kt + 1 < KT) stage(cur ^ 1, kt + 1);

    const int k0 = kt*64;
    if (k0 <= R0 + 31) {
      const u16* Kw = Ks[cur];
      const u16* Vw = Vs[cur];

      // ---- QK^T (swapped): S^T[k][q] ----
      bf16x8 ka[2][4];
#pragma unroll
      for (int st = 0; st < 2; ++st)
#pragma unroll
        for (int j = 0; j < 4; ++j) {
          const int rk = st*32 + ql;
          const int c = (2*j + hi) ^ (rk & 7);
          ka[st][j] = *(const bf16x8*)&Kw[rk*64 + c*8];
        }
      f32x16 s0 = (f32x16)(0.f), s1 = (f32x16)(0.f);
#pragma unroll
      for (int j = 0; j < 4; ++j) {
        s0 = __builtin_amdgcn_mfma_f32_32x32x16_bf16(ka[0][j], qf[j], s0, 0, 0, 0);
        s1 = __builtin_amdgcn_mfma_f32_32x32x16_bf16(ka[1][j], qf[j], s1, 0, 0, 0);
      }

      // ---- scale (+ causal mask on diagonal band) ----
#pragma unroll
      for (int r = 0; r < 16; ++r) { s0[r] *= SCL; s1[r] *= SCL; }
      if (k0 + 63 > R0) {
        const int base = k0 - R0;
#pragma unroll
        for (int r = 0; r < 16; ++r) {
          const int kl = (r&3) + 8*(r>>2) + hi4;
          s0[r] = (ql >= base + kl)      ? s0[r] : -1e30f;
          s1[r] = (ql >= base + 32 + kl) ? s1[r] : -1e30f;
        }
      }

      // ---- row max: lane-local tree + pair combine (shfl_xor 32) ----
      float t[16];
#pragma unroll
      for (int r = 0; r < 16; ++r) t[r] = fmaxf(s0[r], s1[r]);
#pragma unroll
      for (int w = 8; w >= 1; w >>= 1)
#pragma unroll
        for (int r = 0; r < w; ++r) t[r] = fmaxf(t[r], t[r+w]);
      const float mx = fmaxf(t[0], __shfl_xor(t[0], 32, 64));

      // ---- defer-max (T13) ----
      if (__any(mx > m_run + THR2)) {
        const float mn = fmaxf(m_run, mx);
        const float al = __builtin_exp2f(m_run - mn);
        m_run = mn;
        l_run *= al;
#pragma unroll
        for (int r = 0; r < 16; ++r) { o0[r] *= al; o1[r] *= al; }
      }

      // ---- p = 2^(s - m), row sum ----
      float e0[16], e1[16];
#pragma unroll
      for (int r = 0; r < 16; ++r) {
        e0[r] = __builtin_exp2f(s0[r] - m_run);
        e1[r] = __builtin_exp2f(s1[r] - m_run);
      }
#pragma unroll
      for (int r = 0; r < 16; ++r) t[r] = e0[r] + e1[r];
#pragma unroll
      for (int w = 8; w >= 1; w >>= 1)
#pragma unroll
        for (int r = 0; r < w; ++r) t[r] += t[r+w];
      l_run += t[0] + __shfl_xor(t[0], 32, 64);

      // ---- P^T -> bf16 B-operand fragments (cvt_pk + shfl_xor 32) ----
      // target: lane (ql,hi) word w holds P[ql][k = sl*16 + hi*8 + 2w,2w+1]
      bf16x8 pb[4];
#pragma unroll
      for (int sl = 0; sl < 4; ++sl) {
        const float* e = (sl < 2) ? e0 : e1;
        const int o8 = (sl & 1) * 8;
        u32 Aw = cvtpk(e[o8+0], e[o8+1]);   // own k(base+0,1)   [crow 0,1]
        u32 Bw = cvtpk(e[o8+2], e[o8+3]);   // own k(base+2,3)
        u32 Cw = cvtpk(e[o8+4], e[o8+5]);   // own k(base+8,9)   [crow 8,9]
        u32 Dw = cvtpk(e[o8+6], e[o8+7]);   // own k(base+10,11)
        u32 pA = __shfl_xor(Aw, 32, 64);    // partner's A
        u32 pB = __shfl_xor(Bw, 32, 64);
        u32 pC = __shfl_xor(Cw, 32, 64);
        u32 pD = __shfl_xor(Dw, 32, 64);
        u32 w0 = hi ? pC : Aw;
        u32 w1 = hi ? pD : Bw;
        u32 w2 = hi ? Cw : pA;
        u32 w3 = hi ? Dw : pB;
        union { u32x4v u; bf16x8 v; } uu;
        uu.u = (u32x4v){w0, w1, w2, w3};
        pb[sl] = uu.v;
      }

      // ---- PV: O^T[d][q] += V^T[d][k] * P^T[k][q] ----
#pragma unroll
      for (int sl = 0; sl < 4; ++sl) {
        const int c0 = 2*sl + hi;
        const int d0 = ql,      ca = (c0 ^ (d0 & 7));
        const int d1 = 32 + ql, cb = (c0 ^ (d1 & 7));
        bf16x8 va0 = *(const bf16x8*)&Vw[d0*64 + ca*8];
        bf16x8 va1 = *(const bf16x8*)&Vw[d1*64 + cb*8];
        o0 = __builtin_amdgcn_mfma_f32_32x32x16_bf16(va0, pb[sl], o0, 0, 0, 0);
        o1 = __builtin_amdgcn_mfma_f32_32x32x16_bf16(va1, pb[sl], o1, 0, 0, 0);
      }
    }
    __syncthreads();
  }

  // ---- epilogue: O[q][d], packed 4-wide stores ----
  const float inv = 1.0f / l_run;
  u16* Orow = O + (size_t)(b*SEQ + R0 + ql)*DMODEL + h*64;
#pragma unroll
  for (int rb = 0; rb < 4; ++rb) {
    u16x4 wA, wB;
#pragma unroll
    for (int j = 0; j < 4; ++j) {
      wA[j] = f2bf(o0[rb*4 + j] * inv);
      wB[j] = f2bf(o1[rb*4 + j] * inv);
    }
    *(u16x4*)(Orow + 8*rb + hi4)      = wA;
    *(u16x4*)(Orow + 32 + 8*rb + hi4) = wB;
  }
}

// ---------------- launch ----------------
extern "C" void kernel_launch(void* const* d_in, const int* in_sizes, int n_in,
                              void* d_out, int out_size, void* d_ws, size_t ws_size,
                              hipStream_t stream) {
  const float* x  = (const float*)d_in[0];
  const float* Wq = (const float*)d_in[1];
  const float* Wk = (const float*)d_in[2];
  const float* Wv = (const float*)d_in[3];
  const float* Wo = (const float*)d_in[4];
  const int* pos  = (const int*)d_in[5];
  float* out = (float*)d_out;

  const size_t SZ_X   = (size_t)MROWS*DMODEL*2;
  const size_t SZ_W   = (size_t)DMODEL*DMODEL*2;
  const size_t SZ_TAB = (size_t)SEQ*32*4;
  char* w = (char*)d_ws;
  u16* xb   = (u16*)(w);
  u16* Wqb  = (u16*)(w + SZ_X);
  u16* Wkb  = (u16*)(w + SZ_X + SZ_W);
  u16* Wvb  = (u16*)(w + SZ_X + 2*SZ_W);
  u16* Wob  = (u16*)(w + SZ_X + 3*SZ_W);
  float* cosT = (float*)(w + SZ_X + 4*SZ_W);
  float* sinT = (float*)(w + SZ_X + 4*SZ_W + SZ_TAB);
  u16* Qb   = (u16*)(w + SZ_X + 4*SZ_W + 2*SZ_TAB);
  u16* Kb   = (u16*)(w + 2*SZ_X + 4*SZ_W + 2*SZ_TAB);
  u16* Vtmp = (u16*)(w + 3*SZ_X + 4*SZ_W + 2*SZ_TAB);   // reused as O
  u16* Vt   = (u16*)(w + 4*SZ_X + 4*SZ_W + 2*SZ_TAB);
  const size_t need = 5*SZ_X + 4*SZ_W + 2*SZ_TAB;
  if (ws_size < need) return;

  k_cvt<<<(MROWS*DMODEL/4 + 255)/256, 256, 0, stream>>>(x, xb, MROWS*DMODEL/4);
  k_cvt<<<(DMODEL*DMODEL/4 + 255)/256, 256, 0, stream>>>(Wq, Wqb, DMODEL*DMODEL/4);
  k_cvt<<<(DMODEL*DMODEL/4 + 255)/256, 256, 0, stream>>>(Wk, Wkb, DMODEL*DMODEL/4);
  k_cvt<<<(DMODEL*DMODEL/4 + 255)/256, 256, 0, stream>>>(Wv, Wvb, DMODEL*DMODEL/4);
  k_cvt<<<(DMODEL*DMODEL/4 + 255)/256, 256, 0, stream>>>(Wo, Wob, DMODEL*DMODEL/4);
  k_rope_tab<<<SEQ*32/256, 256, 0, stream>>>(pos, cosT, sinT);

  dim3 gproj(MROWS/128, DMODEL/128);
  k_gemm_bt<1><<<gproj, 256, 0, stream>>>(xb, Wqb, Qb, cosT, sinT);
  k_gemm_bt<1><<<gproj, 256, 0, stream>>>(xb, Wkb, Kb, cosT, sinT);
  k_gemm_bt<0><<<gproj, 256, 0, stream>>>(xb, Wvb, Vtmp, cosT, sinT);
  k_transpose_v<<<dim3(SEQ/64, BATCH*NHEADS), 256, 0, stream>>>(Vtmp, Vt);
  k_attn<<<dim3(BATCH*NHEADS, SEQ/256), 512, 0, stream>>>(Qb, Kb, Vt, Vtmp /*O*/);
  k_gemm_bt<2><<<gproj, 256, 0, stream>>>(Vtmp /*O*/, Wob, out, cosT, sinT);
}

// Round 6
// 204.984 us; speedup vs baseline: 3.1123x; 1.1089x over previous
//
#include <hip/hip_runtime.h>
#include <hip/hip_bf16.h>
#include <math.h>

#define SEQ 2048
#define BATCH 4
#define MROWS (BATCH*SEQ)     // 8192
#define DMODEL 1024
#define NHEADS 16
#define DKH 64

typedef float f32x4 __attribute__((ext_vector_type(4)));
typedef float f32x16 __attribute__((ext_vector_type(16)));
typedef __bf16 bf16x8 __attribute__((ext_vector_type(8)));
typedef unsigned short u16;
typedef unsigned int u32;
typedef u16 u16x4 __attribute__((ext_vector_type(4)));
typedef u16 u16x8 __attribute__((ext_vector_type(8)));
typedef u32 u32x4v __attribute__((ext_vector_type(4)));

__device__ __forceinline__ u16 f2bf(float f) {
  union { float f; unsigned u; } v; v.f = f;
  unsigned r = v.u + 0x7FFFu + ((v.u >> 16) & 1u);
  return (u16)(r >> 16);
}

__device__ __forceinline__ void async_copy16(const void* g, void* l) {
  __builtin_amdgcn_global_load_lds(
      (const __attribute__((address_space(1))) void*)g,
      (__attribute__((address_space(3))) void*)l, 16, 0, 0);
}

__device__ __forceinline__ u32 cvtpk(float lo, float hi) {
  u32 r;
  asm("v_cvt_pk_bf16_f32 %0, %1, %2" : "=v"(r) : "v"(lo), "v"(hi));
  return r;
}

// ---------------- prep: x cvt + 4 W cvts + RoPE tables, one launch ---------
__global__ __launch_bounds__(256) void k_prep(
    const float* __restrict__ x,
    const float* __restrict__ Wq, const float* __restrict__ Wk,
    const float* __restrict__ Wv, const float* __restrict__ Wo,
    const int* __restrict__ pos,
    u16* __restrict__ xb, u16* __restrict__ Wqb, u16* __restrict__ Wkb,
    u16* __restrict__ Wvb, u16* __restrict__ Wob,
    float* __restrict__ cosT, float* __restrict__ sinT)
{
  const int bid = blockIdx.x, tid = threadIdx.x;
  if (bid < 8192) {                       // x: 2M float4
    int i = bid*256 + tid;
    float4 v = ((const float4*)x)[i];
    u16x4 o; o[0]=f2bf(v.x); o[1]=f2bf(v.y); o[2]=f2bf(v.z); o[3]=f2bf(v.w);
    ((u16x4*)xb)[i] = o;
  } else if (bid < 12288) {               // W: 4 x 1024 blocks x 256 f4
    int wi = (bid - 8192) >> 10;
    const float* src = (wi==0)?Wq:(wi==1)?Wk:(wi==2)?Wv:Wo;
    u16* dst = (wi==0)?Wqb:(wi==1)?Wkb:(wi==2)?Wvb:Wob;
    int i = ((bid - 8192) & 1023)*256 + tid;
    float4 v = ((const float4*)src)[i];
    u16x4 o; o[0]=f2bf(v.x); o[1]=f2bf(v.y); o[2]=f2bf(v.z); o[3]=f2bf(v.w);
    ((u16x4*)dst)[i] = o;
  } else {                                // rope tables: SEQ*32
    int i = (bid - 12288)*256 + tid;
    int s = i >> 5, j = i & 31;
    double p = (double)pos[s];
    double inv = pow(10000.0, -(double)j / 32.0);
    double a = p * inv;
    cosT[i] = (float)cos(a);
    sinT[i] = (float)sin(a);
  }
}

// ---------------- GEMM: C[m,n] = sum_k A[m,k]*W[n,k] ----------------
// MODE 0: fused QKV (grid y=24; proj=bn>>3: 0=Q rope*SCL, 1=K rope, 2=V->Vt)
// MODE 1: out-proj, f32 output (grid y=8)
template<int MODE>
__global__ __launch_bounds__(256) void k_gemm_all(
    const u16* __restrict__ A,
    const u16* __restrict__ W0, const u16* __restrict__ W1,
    const u16* __restrict__ W2,
    u16* __restrict__ Qo, u16* __restrict__ Ko, u16* __restrict__ Vto,
    float* __restrict__ Fo,
    const float* __restrict__ cosT, const float* __restrict__ sinT)
{
  __shared__ u16 Asl[128*32];
  __shared__ u16 Bsl[128*32];
  const int bm = blockIdx.x, bn = blockIdx.y;
  const int tid = threadIdx.x;
  const int wave = tid >> 6, lane = tid & 63;
  const int lg = lane >> 4, lr = lane & 15;
  const int wm = wave >> 1, wn = wave & 1;

  int proj, bnl;
  const u16* W;
  if constexpr (MODE == 0) {
    proj = bn >> 3; bnl = bn & 7;
    W = (proj == 0) ? W0 : (proj == 1) ? W1 : W2;
  } else {
    proj = 3; bnl = bn; W = W0;
  }

  f32x4 acc[4][4];
#pragma unroll
  for (int i = 0; i < 4; ++i)
#pragma unroll
    for (int j = 0; j < 4; ++j) acc[i][j] = (f32x4){0,0,0,0};

  const int srow = lane >> 2;
  const int sk8  = (lane & 3) * 8;

  for (int kt = 0; kt < 32; ++kt) {
    const int k0 = kt * 32;
#pragma unroll
    for (int i = 0; i < 2; ++i) {
      const u16* ga = A + (size_t)(bm*128 + i*64 + wave*16 + srow)*DMODEL + k0 + sk8;
      const u16* gb = W + (size_t)(bnl*128 + i*64 + wave*16 + srow)*DMODEL + k0 + sk8;
      async_copy16(ga, (char*)Asl + i*4096 + wave*1024);
      async_copy16(gb, (char*)Bsl + i*4096 + wave*1024);
    }
    __syncthreads();
    bf16x8 af[4], bfr[4];
#pragma unroll
    for (int mi = 0; mi < 4; ++mi)
      af[mi] = *(const bf16x8*)&Asl[(wm*64 + mi*16 + lr)*32 + lg*8];
#pragma unroll
    for (int ni = 0; ni < 4; ++ni)
      bfr[ni] = *(const bf16x8*)&Bsl[(wn*64 + ni*16 + lr)*32 + lg*8];
#pragma unroll
    for (int mi = 0; mi < 4; ++mi)
#pragma unroll
      for (int ni = 0; ni < 4; ++ni)
        acc[mi][ni] = __builtin_amdgcn_mfma_f32_16x16x32_bf16(af[mi], bfr[ni], acc[mi][ni], 0, 0, 0);
    __syncthreads();
  }

#pragma unroll
  for (int mi = 0; mi < 4; ++mi) {
    const int row0 = bm*128 + wm*64 + mi*16 + lg*4;
#pragma unroll
    for (int ni = 0; ni < 4; ++ni) {
      const int col = bnl*128 + wn*64 + ni*16 + lr;
      f32x4 a = acc[mi][ni];
      if constexpr (MODE == 1) {
#pragma unroll
        for (int r = 0; r < 4; ++r) Fo[(size_t)(row0+r)*DMODEL + col] = a[r];
      } else {
        if (proj == 2) {        // V: write transposed (b,h,d,s), u16x4 in s
          const int hh = col >> 6, dd = col & 63;
          const int s0r = row0 & (SEQ-1);
          const int bb = row0 >> 11;
          u16x4 wv;
#pragma unroll
          for (int r = 0; r < 4; ++r) wv[r] = f2bf(a[r]);
          *(u16x4*)&Vto[((size_t)((bb*16+hh)*64 + dd))*SEQ + s0r] = wv;
        } else {                // Q/K: RoPE (Q additionally pre-scaled)
          u16* C = (proj == 0) ? Qo : Ko;
          const float scl = (proj == 0) ? 0.18033688f : 1.0f;  // 0.125*log2e
          const int dd = col & 63;
          const int j = dd >> 1;
          const float sgn = (dd & 1) ? 1.0f : -1.0f;
#pragma unroll
          for (int r = 0; r < 4; ++r) {
            const int s = (row0 + r) & (SEQ-1);
            float v = a[r];
            float pv = __shfl_xor(v, 1, 64);
            float c = cosT[s*32 + j], sn = sinT[s*32 + j];
            C[(size_t)(row0+r)*DMODEL + col] = f2bf((v*c + sgn*pv*sn) * scl);
          }
        }
      }
    }
  }
}

// ---------------- causal flash attention v4 ----------------
// Swapped-QK 32x32, K-row permutation (swap bits 2,3) aligns C/D rows with
// PV B-operand layout -> P build is pure lane-local cvt_pk (zero shuffles).
// Row-sum via MFMA ones-trick. Q pre-scaled by 0.125*log2e in projection.
__global__ __launch_bounds__(512) void k_attn(
    const u16* __restrict__ Q, const u16* __restrict__ K,
    const u16* __restrict__ Vt, u16* __restrict__ O)
{
  const int bh = blockIdx.x;
  const int qt = (gridDim.y - 1) - blockIdx.y;   // LPT: heaviest q-tiles first
  const int b = bh >> 4, h = bh & 15;
  const int wave = threadIdx.x >> 6, lane = threadIdx.x & 63;
  const int ql = lane & 31, hi = lane >> 5, hi4 = hi * 4;
  const int R0 = qt*256 + wave*32;

  __shared__ alignas(16) u16 Ks[2][64*64];
  __shared__ alignas(16) u16 Vs[2][64*64];

  const u16* Qb = Q + (size_t)(b*SEQ)*DMODEL + h*64;
  const u16* Kb = K + (size_t)(b*SEQ)*DMODEL + h*64;
  const u16* Vb = Vt + (size_t)(bh*64)*SEQ;

  // Q as B-operand: lane holds Q[R0+ql][j*16 + hi*8 + i]
  bf16x8 qf[4];
#pragma unroll
  for (int j = 0; j < 4; ++j)
    qf[j] = *(const bf16x8*)(Qb + (size_t)(R0 + ql)*DMODEL + j*16 + hi*8);

  // ones A-fragment for l-accumulation
  union { u16x8 u; bf16x8 v; } onesu;
#pragma unroll
  for (int i = 0; i < 8; ++i) onesu.u[i] = 0x3F80;
  const bf16x8 ones = onesu.v;

  f32x16 o0 = (f32x16)(0.f), o1 = (f32x16)(0.f);   // O^T accum, d-tiles 0,1
  f32x16 lacc = (f32x16)(0.f);                     // row-sum accum (reg0 used)
  float m_run = -INFINITY;
  const float THR2 = 11.5415603f;   // 8 * log2(e)

  const int KT = (qt + 1) * 4;

  // K-row permutation: swap bits 2,3 (involution)
  const int qp = (ql & ~12) | ((ql & 4) << 1) | ((ql & 8) >> 1);

  // stage one KV tile: 512 threads x (1 K-chunk + 1 V-chunk of 16B)
  // pre-swizzled source (rule #21): LDS[row][c] = global[row][c ^ (row&7)]
  auto stage = [&](int buf, int kt) {
    const int idx = threadIdx.x;            // 0..511
    const int row = idx >> 3, ch = idx & 7;
    const int sch = (ch ^ (row & 7)) * 8;
    const int k0 = kt * 64;
    async_copy16(Kb + (size_t)(k0 + row)*DMODEL + sch, (char*)Ks[buf] + idx*16);
    async_copy16(Vb + (size_t)row*SEQ + k0 + sch,      (char*)Vs[buf] + idx*16);
  };

  stage(0, 0);
  __syncthreads();

  for (int kt = 0; kt < KT; ++kt) {
    const int cur = kt & 1;
    if (kt + 1 < KT) stage(cur ^ 1, kt + 1);

    const int k0 = kt*64;
    if (k0 <= R0 + 31) {
      const u16* Kw = Ks[cur];
      const u16* Vw = Vs[cur];

      // ---- QK^T (swapped, permuted rows): A-row ql <- K[st*32 + qp] ----
      bf16x8 ka[2][4];
#pragma unroll
      for (int st = 0; st < 2; ++st)
#pragma unroll
        for (int j = 0; j < 4; ++j) {
          const int rk = st*32 + qp;
          const int c = (2*j + hi) ^ (rk & 7);
          ka[st][j] = *(const bf16x8*)&Kw[rk*64 + c*8];
        }
      f32x16 s0 = (f32x16)(0.f), s1 = (f32x16)(0.f);
#pragma unroll
      for (int j = 0; j < 4; ++j) {
        s0 = __builtin_amdgcn_mfma_f32_32x32x16_bf16(ka[0][j], qf[j], s0, 0, 0, 0);
        s1 = __builtin_amdgcn_mfma_f32_32x32x16_bf16(ka[1][j], qf[j], s1, 0, 0, 0);
      }

      // ---- causal mask (diagonal band only); scores pre-scaled via Q ----
      if (k0 + 63 > R0) {
        const int base = k0 - R0;
#pragma unroll
        for (int r = 0; r < 16; ++r) {
          const int kl = (r & 7) + (hi << 3) + ((r & 8) << 1);  // permuted map
          s0[r] = (ql >= base + kl)      ? s0[r] : -1e30f;
          s1[r] = (ql >= base + 32 + kl) ? s1[r] : -1e30f;
        }
      }

      // ---- row max: lane-local tree + pair combine ----
      float t[16];
#pragma unroll
      for (int r = 0; r < 16; ++r) t[r] = fmaxf(s0[r], s1[r]);
#pragma unroll
      for (int w = 8; w >= 1; w >>= 1)
#pragma unroll
        for (int r = 0; r < w; ++r) t[r] = fmaxf(t[r], t[r+w]);
      const float mx = fmaxf(t[0], __shfl_xor(t[0], 32, 64));

      // ---- defer-max (T13) ----
      if (__any(mx > m_run + THR2)) {
        const float mn = fmaxf(m_run, mx);
        const float al = __builtin_exp2f(m_run - mn);
        m_run = mn;
        lacc[0] *= al;
#pragma unroll
        for (int r = 0; r < 16; ++r) { o0[r] *= al; o1[r] *= al; }
      }

      // ---- p = 2^(s - m) ----
      float e0[16], e1[16];
#pragma unroll
      for (int r = 0; r < 16; ++r) {
        e0[r] = __builtin_exp2f(s0[r] - m_run);
        e1[r] = __builtin_exp2f(s1[r] - m_run);
      }

      // ---- P^T -> bf16 B fragments: pure lane-local (permutation-aligned) --
      bf16x8 pb[4];
#pragma unroll
      for (int sl = 0; sl < 4; ++sl) {
        const float* e = (sl < 2) ? e0 : e1;
        const int o8 = (sl & 1) * 8;
        u32 w0 = cvtpk(e[o8+0], e[o8+1]);
        u32 w1 = cvtpk(e[o8+2], e[o8+3]);
        u32 w2 = cvtpk(e[o8+4], e[o8+5]);
        u32 w3 = cvtpk(e[o8+6], e[o8+7]);
        union { u32x4v u; bf16x8 v; } uu;
        uu.u = (u32x4v){w0, w1, w2, w3};
        pb[sl] = uu.v;
      }

      // ---- PV + l-accum: O^T[d][q] += V^T[d][k] P^T[k][q]; l += 1^T P ----
#pragma unroll
      for (int sl = 0; sl < 4; ++sl) {
        const int c0 = 2*sl + hi;
        const int d0 = ql,      ca = (c0 ^ (d0 & 7));
        const int d1 = 32 + ql, cb = (c0 ^ (d1 & 7));
        bf16x8 va0 = *(const bf16x8*)&Vw[d0*64 + ca*8];
        bf16x8 va1 = *(const bf16x8*)&Vw[d1*64 + cb*8];
        o0 = __builtin_amdgcn_mfma_f32_32x32x16_bf16(va0, pb[sl], o0, 0, 0, 0);
        o1 = __builtin_amdgcn_mfma_f32_32x32x16_bf16(va1, pb[sl], o1, 0, 0, 0);
        lacc = __builtin_amdgcn_mfma_f32_32x32x16_bf16(ones, pb[sl], lacc, 0, 0, 0);
      }
    }
    __syncthreads();
  }

  // ---- epilogue: O[q][d], packed 4-wide stores ----
  const float inv = 1.0f / lacc[0];
  u16* Orow = O + (size_t)(b*SEQ + R0 + ql)*DMODEL + h*64;
#pragma unroll
  for (int rb = 0; rb < 4; ++rb) {
    u16x4 wA, wB;
#pragma unroll
    for (int j = 0; j < 4; ++j) {
      wA[j] = f2bf(o0[rb*4 + j] * inv);
      wB[j] = f2bf(o1[rb*4 + j] * inv);
    }
    *(u16x4*)(Orow + 8*rb + hi4)      = wA;
    *(u16x4*)(Orow + 32 + 8*rb + hi4) = wB;
  }
}

// ---------------- launch ----------------
extern "C" void kernel_launch(void* const* d_in, const int* in_sizes, int n_in,
                              void* d_out, int out_size, void* d_ws, size_t ws_size,
                              hipStream_t stream) {
  const float* x  = (const float*)d_in[0];
  const float* Wq = (const float*)d_in[1];
  const float* Wk = (const float*)d_in[2];
  const float* Wv = (const float*)d_in[3];
  const float* Wo = (const float*)d_in[4];
  const int* pos  = (const int*)d_in[5];
  float* out = (float*)d_out;

  const size_t SZ_X   = (size_t)MROWS*DMODEL*2;   // 16 MiB
  const size_t SZ_W   = (size_t)DMODEL*DMODEL*2;  // 2 MiB
  const size_t SZ_TAB = (size_t)SEQ*32*4;
  char* w = (char*)d_ws;
  u16* xb   = (u16*)(w);
  u16* Wqb  = (u16*)(w + SZ_X);
  u16* Wkb  = (u16*)(w + SZ_X + SZ_W);
  u16* Wvb  = (u16*)(w + SZ_X + 2*SZ_W);
  u16* Wob  = (u16*)(w + SZ_X + 3*SZ_W);
  float* cosT = (float*)(w + SZ_X + 4*SZ_W);
  float* sinT = (float*)(w + SZ_X + 4*SZ_W + SZ_TAB);
  u16* Qb   = (u16*)(w + SZ_X + 4*SZ_W + 2*SZ_TAB);
  u16* Kb   = (u16*)(w + 2*SZ_X + 4*SZ_W + 2*SZ_TAB);
  u16* Ob   = (u16*)(w + 3*SZ_X + 4*SZ_W + 2*SZ_TAB);
  u16* Vt   = (u16*)(w + 4*SZ_X + 4*SZ_W + 2*SZ_TAB);
  const size_t need = 5*SZ_X + 4*SZ_W + 2*SZ_TAB;
  if (ws_size < need) return;

  k_prep<<<12544, 256, 0, stream>>>(x, Wq, Wk, Wv, Wo, pos,
                                    xb, Wqb, Wkb, Wvb, Wob, cosT, sinT);
  k_gemm_all<0><<<dim3(MROWS/128, 24), 256, 0, stream>>>(
      xb, Wqb, Wkb, Wvb, Qb, Kb, Vt, nullptr, cosT, sinT);
  k_attn<<<dim3(BATCH*NHEADS, SEQ/256), 512, 0, stream>>>(Qb, Kb, Vt, Ob);
  k_gemm_all<1><<<dim3(MROWS/128, 8), 256, 0, stream>>>(
      Ob, Wob, nullptr, nullptr, nullptr, nullptr, nullptr, out, cosT, sinT);
}

// Round 7
// 200.117 us; speedup vs baseline: 3.1879x; 1.0243x over previous
//
#include <hip/hip_runtime.h>
#include <hip/hip_bf16.h>
#include <math.h>

#define SEQ 2048
#define BATCH 4
#define MROWS (BATCH*SEQ)     // 8192
#define DMODEL 1024
#define NHEADS 16
#define DKH 64

typedef float f32x4 __attribute__((ext_vector_type(4)));
typedef float f32x16 __attribute__((ext_vector_type(16)));
typedef __bf16 bf16x8 __attribute__((ext_vector_type(8)));
typedef unsigned short u16;
typedef unsigned int u32;
typedef u16 u16x4 __attribute__((ext_vector_type(4)));
typedef u16 u16x8 __attribute__((ext_vector_type(8)));
typedef u32 u32x4v __attribute__((ext_vector_type(4)));

__device__ __forceinline__ u16 f2bf(float f) {
  union { float f; unsigned u; } v; v.f = f;
  unsigned r = v.u + 0x7FFFu + ((v.u >> 16) & 1u);
  return (u16)(r >> 16);
}

__device__ __forceinline__ void async_copy16(const void* g, void* l) {
  __builtin_amdgcn_global_load_lds(
      (const __attribute__((address_space(1))) void*)g,
      (__attribute__((address_space(3))) void*)l, 16, 0, 0);
}

__device__ __forceinline__ u32 cvtpk(float lo, float hi) {
  u32 r;
  asm("v_cvt_pk_bf16_f32 %0, %1, %2" : "=v"(r) : "v"(lo), "v"(hi));
  return r;
}

// ---------------- prep: x cvt + 4 W cvts + RoPE tables, one launch ---------
__global__ __launch_bounds__(256) void k_prep(
    const float* __restrict__ x,
    const float* __restrict__ Wq, const float* __restrict__ Wk,
    const float* __restrict__ Wv, const float* __restrict__ Wo,
    const int* __restrict__ pos,
    u16* __restrict__ xb, u16* __restrict__ Wqb, u16* __restrict__ Wkb,
    u16* __restrict__ Wvb, u16* __restrict__ Wob,
    float* __restrict__ cosT, float* __restrict__ sinT)
{
  const int bid = blockIdx.x, tid = threadIdx.x;
  if (bid < 8192) {                       // x: 2M float4
    int i = bid*256 + tid;
    float4 v = ((const float4*)x)[i];
    u16x4 o; o[0]=f2bf(v.x); o[1]=f2bf(v.y); o[2]=f2bf(v.z); o[3]=f2bf(v.w);
    ((u16x4*)xb)[i] = o;
  } else if (bid < 12288) {               // W: 4 x 1024 blocks x 256 f4
    int wi = (bid - 8192) >> 10;
    const float* src = (wi==0)?Wq:(wi==1)?Wk:(wi==2)?Wv:Wo;
    u16* dst = (wi==0)?Wqb:(wi==1)?Wkb:(wi==2)?Wvb:Wob;
    int i = ((bid - 8192) & 1023)*256 + tid;
    float4 v = ((const float4*)src)[i];
    u16x4 o; o[0]=f2bf(v.x); o[1]=f2bf(v.y); o[2]=f2bf(v.z); o[3]=f2bf(v.w);
    ((u16x4*)dst)[i] = o;
  } else {                                // rope tables: SEQ*32
    int i = (bid - 12288)*256 + tid;
    int s = i >> 5, j = i & 31;
    double p = (double)pos[s];
    double inv = pow(10000.0, -(double)j / 32.0);
    double a = p * inv;
    cosT[i] = (float)cos(a);
    sinT[i] = (float)sin(a);
  }
}

// ---------------- GEMM v2: 128x256 tile, BK=64, 8 waves, 3-buffer pipeline -
// counted vmcnt(6) + raw s_barrier (no compiler vmcnt(0) drain); XOR-swizzled
// LDS (pre-swizzled global source, swizzled ds_read). C[m,n]=sum_k A[m,k]W[n,k]
// MODE 0: fused QKV (grid y=12; proj=y>>2: 0=Q rope*SCL, 1=K rope, 2=V->Vt)
// MODE 1: out-proj, f32 output (grid y=4)
template<int MODE>
__global__ __launch_bounds__(512) void k_gemm2(
    const u16* __restrict__ A,
    const u16* __restrict__ W0, const u16* __restrict__ W1,
    const u16* __restrict__ W2,
    u16* __restrict__ Qo, u16* __restrict__ Ko, u16* __restrict__ Vto,
    float* __restrict__ Fo,
    const float* __restrict__ cosT, const float* __restrict__ sinT)
{
  __shared__ alignas(16) u16 As[3][128*64];   // 3 x 16 KiB
  __shared__ alignas(16) u16 Bs[3][256*64];   // 3 x 32 KiB  (total 144 KiB)

  const int bm = blockIdx.x;
  int proj, bnl;
  const u16* W;
  if constexpr (MODE == 0) {
    proj = blockIdx.y >> 2; bnl = blockIdx.y & 3;
    W = (proj == 0) ? W0 : (proj == 1) ? W1 : W2;
  } else {
    proj = 3; bnl = blockIdx.y; W = W0;
  }

  const int tid = threadIdx.x;
  const int wave = tid >> 6, lane = tid & 63;
  const int lg = lane >> 4, lr = lane & 15;
  const int wm = wave >> 2, wn = wave & 3;    // 2M x 4N wave grid

  const u16* Ab = A + (size_t)(bm*128)*DMODEL;
  const u16* Wb = W + (size_t)(bnl*256)*DMODEL;

  f32x4 acc[4][4];
#pragma unroll
  for (int i = 0; i < 4; ++i)
#pragma unroll
    for (int j = 0; j < 4; ++j) acc[i][j] = (f32x4){0,0,0,0};

  // stage one K-tile (6 gload_lds/wave): LDS[row][ch] = G[row][ch^(row&7)]
  auto stage = [&](int buf, int kt) {
    const int k0 = kt * 64;
#pragma unroll
    for (int i = 0; i < 2; ++i) {
      const int idx = i*512 + tid;          // 0..1023
      const int row = idx >> 3, ch = idx & 7;
      async_copy16(Ab + (size_t)row*DMODEL + k0 + ((ch ^ (row & 7)) * 8),
                   (char*)As[buf] + idx*16);
    }
#pragma unroll
    for (int i = 0; i < 4; ++i) {
      const int idx = i*512 + tid;          // 0..2047
      const int row = idx >> 3, ch = idx & 7;
      async_copy16(Wb + (size_t)row*DMODEL + k0 + ((ch ^ (row & 7)) * 8),
                   (char*)Bs[buf] + idx*16);
    }
  };

  const int NT = DMODEL / 64;   // 16
  stage(0, 0);
  stage(1, 1);
  asm volatile("s_waitcnt vmcnt(6)" ::: "memory");   // tile0 landed, tile1 flying
  __builtin_amdgcn_sched_barrier(0);
  __builtin_amdgcn_s_barrier();

  for (int t = 0; t < NT; ++t) {
    const int cur = t % 3;
    if (t + 2 < NT) stage((t + 2) % 3, t + 2);   // issue-ahead (depth 2)

    const u16* Aw = As[cur];
    const u16* Bw = Bs[cur];
    __builtin_amdgcn_s_setprio(1);
#pragma unroll
    for (int kk = 0; kk < 2; ++kk) {
      bf16x8 bfr[4];
#pragma unroll
      for (int ni = 0; ni < 4; ++ni) {
        const int row = wn*64 + ni*16 + lr;
        bfr[ni] = *(const bf16x8*)&Bw[row*64 + (((kk*4 + lg) ^ (row & 7)) * 8)];
      }
#pragma unroll
      for (int mi = 0; mi < 4; ++mi) {
        const int row = wm*64 + mi*16 + lr;
        bf16x8 af = *(const bf16x8*)&Aw[row*64 + (((kk*4 + lg) ^ (row & 7)) * 8)];
#pragma unroll
        for (int ni = 0; ni < 4; ++ni)
          acc[mi][ni] = __builtin_amdgcn_mfma_f32_16x16x32_bf16(af, bfr[ni], acc[mi][ni], 0, 0, 0);
      }
    }
    __builtin_amdgcn_s_setprio(0);

    if (t + 1 < NT) {
      if (t + 2 < NT) {        // 12 outstanding -> wait oldest 6 (tile t+1)
        asm volatile("s_waitcnt vmcnt(6)" ::: "memory");
      } else {                 // only tile t+1's 6 left
        asm volatile("s_waitcnt vmcnt(0)" ::: "memory");
      }
      __builtin_amdgcn_sched_barrier(0);
      __builtin_amdgcn_s_barrier();
    }
  }

  // ---- epilogue ----
#pragma unroll
  for (int mi = 0; mi < 4; ++mi) {
    const int row0 = bm*128 + wm*64 + mi*16 + lg*4;
#pragma unroll
    for (int ni = 0; ni < 4; ++ni) {
      const int col = bnl*256 + wn*64 + ni*16 + lr;
      f32x4 a = acc[mi][ni];
      if constexpr (MODE == 1) {
#pragma unroll
        for (int r = 0; r < 4; ++r) Fo[(size_t)(row0+r)*DMODEL + col] = a[r];
      } else {
        if (proj == 2) {        // V: write transposed (b,h,d,s), u16x4 in s
          const int hh = col >> 6, dd = col & 63;
          const int s0r = row0 & (SEQ-1);
          const int bb = row0 >> 11;
          u16x4 wv;
#pragma unroll
          for (int r = 0; r < 4; ++r) wv[r] = f2bf(a[r]);
          *(u16x4*)&Vto[((size_t)((bb*16+hh)*64 + dd))*SEQ + s0r] = wv;
        } else {                // Q/K: RoPE (Q additionally pre-scaled)
          u16* C = (proj == 0) ? Qo : Ko;
          const float scl = (proj == 0) ? 0.18033688f : 1.0f;  // 0.125*log2e
          const int dd = col & 63;
          const int j = dd >> 1;
          const float sgn = (dd & 1) ? 1.0f : -1.0f;
#pragma unroll
          for (int r = 0; r < 4; ++r) {
            const int s = (row0 + r) & (SEQ-1);
            float v = a[r];
            float pv = __shfl_xor(v, 1, 64);
            float c = cosT[s*32 + j], sn = sinT[s*32 + j];
            C[(size_t)(row0+r)*DMODEL + col] = f2bf((v*c + sgn*pv*sn) * scl);
          }
        }
      }
    }
  }
}

// ---------------- causal flash attention v4 ----------------
// Swapped-QK 32x32, K-row permutation (swap bits 2,3) aligns C/D rows with
// PV B-operand layout -> P build is pure lane-local cvt_pk (zero shuffles).
// Row-sum via MFMA ones-trick. Q pre-scaled by 0.125*log2e in projection.
__global__ __launch_bounds__(512) void k_attn(
    const u16* __restrict__ Q, const u16* __restrict__ K,
    const u16* __restrict__ Vt, u16* __restrict__ O)
{
  const int bh = blockIdx.x;
  const int qt = (gridDim.y - 1) - blockIdx.y;   // LPT: heaviest q-tiles first
  const int b = bh >> 4, h = bh & 15;
  const int wave = threadIdx.x >> 6, lane = threadIdx.x & 63;
  const int ql = lane & 31, hi = lane >> 5, hi4 = hi * 4;
  const int R0 = qt*256 + wave*32;

  __shared__ alignas(16) u16 Ks[2][64*64];
  __shared__ alignas(16) u16 Vs[2][64*64];

  const u16* Qb = Q + (size_t)(b*SEQ)*DMODEL + h*64;
  const u16* Kb = K + (size_t)(b*SEQ)*DMODEL + h*64;
  const u16* Vb = Vt + (size_t)(bh*64)*SEQ;

  // Q as B-operand: lane holds Q[R0+ql][j*16 + hi*8 + i]
  bf16x8 qf[4];
#pragma unroll
  for (int j = 0; j < 4; ++j)
    qf[j] = *(const bf16x8*)(Qb + (size_t)(R0 + ql)*DMODEL + j*16 + hi*8);

  // ones A-fragment for l-accumulation
  union { u16x8 u; bf16x8 v; } onesu;
#pragma unroll
  for (int i = 0; i < 8; ++i) onesu.u[i] = 0x3F80;
  const bf16x8 ones = onesu.v;

  f32x16 o0 = (f32x16)(0.f), o1 = (f32x16)(0.f);   // O^T accum, d-tiles 0,1
  f32x16 lacc = (f32x16)(0.f);                     // row-sum accum (reg0 used)
  float m_run = -INFINITY;
  const float THR2 = 11.5415603f;   // 8 * log2(e)

  const int KT = (qt + 1) * 4;

  // K-row permutation: swap bits 2,3 (involution)
  const int qp = (ql & ~12) | ((ql & 4) << 1) | ((ql & 8) >> 1);

  // stage one KV tile: 512 threads x (1 K-chunk + 1 V-chunk of 16B)
  // pre-swizzled source (rule #21): LDS[row][c] = global[row][c ^ (row&7)]
  auto stage = [&](int buf, int kt) {
    const int idx = threadIdx.x;            // 0..511
    const int row = idx >> 3, ch = idx & 7;
    const int sch = (ch ^ (row & 7)) * 8;
    const int k0 = kt * 64;
    async_copy16(Kb + (size_t)(k0 + row)*DMODEL + sch, (char*)Ks[buf] + idx*16);
    async_copy16(Vb + (size_t)row*SEQ + k0 + sch,      (char*)Vs[buf] + idx*16);
  };

  stage(0, 0);
  __syncthreads();

  for (int kt = 0; kt < KT; ++kt) {
    const int cur = kt & 1;
    if (kt + 1 < KT) stage(cur ^ 1, kt + 1);

    const int k0 = kt*64;
    if (k0 <= R0 + 31) {
      const u16* Kw = Ks[cur];
      const u16* Vw = Vs[cur];

      // ---- QK^T (swapped, permuted rows): A-row ql <- K[st*32 + qp] ----
      bf16x8 ka[2][4];
#pragma unroll
      for (int st = 0; st < 2; ++st)
#pragma unroll
        for (int j = 0; j < 4; ++j) {
          const int rk = st*32 + qp;
          const int c = (2*j + hi) ^ (rk & 7);
          ka[st][j] = *(const bf16x8*)&Kw[rk*64 + c*8];
        }
      f32x16 s0 = (f32x16)(0.f), s1 = (f32x16)(0.f);
#pragma unroll
      for (int j = 0; j < 4; ++j) {
        s0 = __builtin_amdgcn_mfma_f32_32x32x16_bf16(ka[0][j], qf[j], s0, 0, 0, 0);
        s1 = __builtin_amdgcn_mfma_f32_32x32x16_bf16(ka[1][j], qf[j], s1, 0, 0, 0);
      }

      // ---- causal mask (diagonal band only); scores pre-scaled via Q ----
      if (k0 + 63 > R0) {
        const int base = k0 - R0;
#pragma unroll
        for (int r = 0; r < 16; ++r) {
          const int kl = (r & 7) + (hi << 3) + ((r & 8) << 1);  // permuted map
          s0[r] = (ql >= base + kl)      ? s0[r] : -1e30f;
          s1[r] = (ql >= base + 32 + kl) ? s1[r] : -1e30f;
        }
      }

      // ---- row max: lane-local tree + pair combine ----
      float t[16];
#pragma unroll
      for (int r = 0; r < 16; ++r) t[r] = fmaxf(s0[r], s1[r]);
#pragma unroll
      for (int w = 8; w >= 1; w >>= 1)
#pragma unroll
        for (int r = 0; r < w; ++r) t[r] = fmaxf(t[r], t[r+w]);
      const float mx = fmaxf(t[0], __shfl_xor(t[0], 32, 64));

      // ---- defer-max (T13) ----
      if (__any(mx > m_run + THR2)) {
        const float mn = fmaxf(m_run, mx);
        const float al = __builtin_exp2f(m_run - mn);
        m_run = mn;
        lacc[0] *= al;
#pragma unroll
        for (int r = 0; r < 16; ++r) { o0[r] *= al; o1[r] *= al; }
      }

      // ---- p = 2^(s - m) ----
      float e0[16], e1[16];
#pragma unroll
      for (int r = 0; r < 16; ++r) {
        e0[r] = __builtin_exp2f(s0[r] - m_run);
        e1[r] = __builtin_exp2f(s1[r] - m_run);
      }

      // ---- P^T -> bf16 B fragments: pure lane-local (permutation-aligned) --
      bf16x8 pb[4];
#pragma unroll
      for (int sl = 0; sl < 4; ++sl) {
        const float* e = (sl < 2) ? e0 : e1;
        const int o8 = (sl & 1) * 8;
        u32 w0 = cvtpk(e[o8+0], e[o8+1]);
        u32 w1 = cvtpk(e[o8+2], e[o8+3]);
        u32 w2 = cvtpk(e[o8+4], e[o8+5]);
        u32 w3 = cvtpk(e[o8+6], e[o8+7]);
        union { u32x4v u; bf16x8 v; } uu;
        uu.u = (u32x4v){w0, w1, w2, w3};
        pb[sl] = uu.v;
      }

      // ---- PV + l-accum: O^T[d][q] += V^T[d][k] P^T[k][q]; l += 1^T P ----
#pragma unroll
      for (int sl = 0; sl < 4; ++sl) {
        const int c0 = 2*sl + hi;
        const int d0 = ql,      ca = (c0 ^ (d0 & 7));
        const int d1 = 32 + ql, cb = (c0 ^ (d1 & 7));
        bf16x8 va0 = *(const bf16x8*)&Vw[d0*64 + ca*8];
        bf16x8 va1 = *(const bf16x8*)&Vw[d1*64 + cb*8];
        o0 = __builtin_amdgcn_mfma_f32_32x32x16_bf16(va0, pb[sl], o0, 0, 0, 0);
        o1 = __builtin_amdgcn_mfma_f32_32x32x16_bf16(va1, pb[sl], o1, 0, 0, 0);
        lacc = __builtin_amdgcn_mfma_f32_32x32x16_bf16(ones, pb[sl], lacc, 0, 0, 0);
      }
    }
    __syncthreads();
  }

  // ---- epilogue: O[q][d], packed 4-wide stores ----
  const float inv = 1.0f / lacc[0];
  u16* Orow = O + (size_t)(b*SEQ + R0 + ql)*DMODEL + h*64;
#pragma unroll
  for (int rb = 0; rb < 4; ++rb) {
    u16x4 wA, wB;
#pragma unroll
    for (int j = 0; j < 4; ++j) {
      wA[j] = f2bf(o0[rb*4 + j] * inv);
      wB[j] = f2bf(o1[rb*4 + j] * inv);
    }
    *(u16x4*)(Orow + 8*rb + hi4)      = wA;
    *(u16x4*)(Orow + 32 + 8*rb + hi4) = wB;
  }
}

// ---------------- launch ----------------
extern "C" void kernel_launch(void* const* d_in, const int* in_sizes, int n_in,
                              void* d_out, int out_size, void* d_ws, size_t ws_size,
                              hipStream_t stream) {
  const float* x  = (const float*)d_in[0];
  const float* Wq = (const float*)d_in[1];
  const float* Wk = (const float*)d_in[2];
  const float* Wv = (const float*)d_in[3];
  const float* Wo = (const float*)d_in[4];
  const int* pos  = (const int*)d_in[5];
  float* out = (float*)d_out;

  const size_t SZ_X   = (size_t)MROWS*DMODEL*2;   // 16 MiB
  const size_t SZ_W   = (size_t)DMODEL*DMODEL*2;  // 2 MiB
  const size_t SZ_TAB = (size_t)SEQ*32*4;
  char* w = (char*)d_ws;
  u16* xb   = (u16*)(w);
  u16* Wqb  = (u16*)(w + SZ_X);
  u16* Wkb  = (u16*)(w + SZ_X + SZ_W);
  u16* Wvb  = (u16*)(w + SZ_X + 2*SZ_W);
  u16* Wob  = (u16*)(w + SZ_X + 3*SZ_W);
  float* cosT = (float*)(w + SZ_X + 4*SZ_W);
  float* sinT = (float*)(w + SZ_X + 4*SZ_W + SZ_TAB);
  u16* Qb   = (u16*)(w + SZ_X + 4*SZ_W + 2*SZ_TAB);
  u16* Kb   = (u16*)(w + 2*SZ_X + 4*SZ_W + 2*SZ_TAB);
  u16* Ob   = (u16*)(w + 3*SZ_X + 4*SZ_W + 2*SZ_TAB);
  u16* Vt   = (u16*)(w + 4*SZ_X + 4*SZ_W + 2*SZ_TAB);
  const size_t need = 5*SZ_X + 4*SZ_W + 2*SZ_TAB;
  if (ws_size < need) return;

  k_prep<<<12544, 256, 0, stream>>>(x, Wq, Wk, Wv, Wo, pos,
                                    xb, Wqb, Wkb, Wvb, Wob, cosT, sinT);
  k_gemm2<0><<<dim3(MROWS/128, 12), 512, 0, stream>>>(
      xb, Wqb, Wkb, Wvb, Qb, Kb, Vt, nullptr, cosT, sinT);
  k_attn<<<dim3(BATCH*NHEADS, SEQ/256), 512, 0, stream>>>(Qb, Kb, Vt, Ob);
  k_gemm2<1><<<dim3(MROWS/128, 4), 512, 0, stream>>>(
      Ob, Wob, nullptr, nullptr, nullptr, nullptr, nullptr, out, cosT, sinT);
}

// Round 8
// 199.298 us; speedup vs baseline: 3.2011x; 1.0041x over previous
//
#include <hip/hip_runtime.h>
#include <hip/hip_bf16.h>
#include <math.h>

#define SEQ 2048
#define BATCH 4
#define MROWS (BATCH*SEQ)     // 8192
#define DMODEL 1024
#define NHEADS 16
#define DKH 64

typedef float f32x4 __attribute__((ext_vector_type(4)));
typedef float f32x16 __attribute__((ext_vector_type(16)));
typedef __bf16 bf16x8 __attribute__((ext_vector_type(8)));
typedef unsigned short u16;
typedef unsigned int u32;
typedef u16 u16x4 __attribute__((ext_vector_type(4)));
typedef u16 u16x8 __attribute__((ext_vector_type(8)));
typedef u32 u32x4v __attribute__((ext_vector_type(4)));

__device__ __forceinline__ u16 f2bf(float f) {
  union { float f; unsigned u; } v; v.f = f;
  unsigned r = v.u + 0x7FFFu + ((v.u >> 16) & 1u);
  return (u16)(r >> 16);
}

__device__ __forceinline__ void async_copy16(const void* g, void* l) {
  __builtin_amdgcn_global_load_lds(
      (const __attribute__((address_space(1))) void*)g,
      (__attribute__((address_space(3))) void*)l, 16, 0, 0);
}

__device__ __forceinline__ u32 cvtpk(float lo, float hi) {
  u32 r;
  asm("v_cvt_pk_bf16_f32 %0, %1, %2" : "=v"(r) : "v"(lo), "v"(hi));
  return r;
}

// ---------------- prep: x cvt + 4 W cvts + RoPE tables, one launch ---------
__global__ __launch_bounds__(256) void k_prep(
    const float* __restrict__ x,
    const float* __restrict__ Wq, const float* __restrict__ Wk,
    const float* __restrict__ Wv, const float* __restrict__ Wo,
    const int* __restrict__ pos,
    u16* __restrict__ xb, u16* __restrict__ Wqb, u16* __restrict__ Wkb,
    u16* __restrict__ Wvb, u16* __restrict__ Wob,
    float* __restrict__ cosT, float* __restrict__ sinT)
{
  const int bid = blockIdx.x, tid = threadIdx.x;
  if (bid < 8192) {                       // x: 2M float4
    int i = bid*256 + tid;
    float4 v = ((const float4*)x)[i];
    u16x4 o; o[0]=f2bf(v.x); o[1]=f2bf(v.y); o[2]=f2bf(v.z); o[3]=f2bf(v.w);
    ((u16x4*)xb)[i] = o;
  } else if (bid < 12288) {               // W: 4 x 1024 blocks x 256 f4
    int wi = (bid - 8192) >> 10;
    const float* src = (wi==0)?Wq:(wi==1)?Wk:(wi==2)?Wv:Wo;
    u16* dst = (wi==0)?Wqb:(wi==1)?Wkb:(wi==2)?Wvb:Wob;
    int i = ((bid - 8192) & 1023)*256 + tid;
    float4 v = ((const float4*)src)[i];
    u16x4 o; o[0]=f2bf(v.x); o[1]=f2bf(v.y); o[2]=f2bf(v.z); o[3]=f2bf(v.w);
    ((u16x4*)dst)[i] = o;
  } else {                                // rope tables: SEQ*32
    int i = (bid - 12288)*256 + tid;
    int s = i >> 5, j = i & 31;
    double p = (double)pos[s];
    double inv = pow(10000.0, -(double)j / 32.0);
    double a = p * inv;
    cosT[i] = (float)cos(a);
    sinT[i] = (float)sin(a);
  }
}

// ---------------- GEMM v2: 128x256 tile, BK=64, 8 waves, 3-buffer pipeline -
// counted vmcnt(6) + raw s_barrier; XOR-swizzled LDS (pre-swizzled source).
// XCD-aware 1D grid remap (T1): B%8 = XCD; each XCD keeps 8 fixed A-panels
// (2MB, resident across rounds) + 4 W-panels/round (2MB) in its 4MB L2.
// MODE 0: fused QKV, grid 768 (y=B>>6 in [0,12): proj=y>>2, bnl=y&3)
// MODE 1: out-proj f32, grid 256 (y=B>>6 in [0,4))
template<int MODE>
__global__ __launch_bounds__(512) void k_gemm2(
    const u16* __restrict__ A,
    const u16* __restrict__ W0, const u16* __restrict__ W1,
    const u16* __restrict__ W2,
    u16* __restrict__ Qo, u16* __restrict__ Ko, u16* __restrict__ Vto,
    float* __restrict__ Fo,
    const float* __restrict__ cosT, const float* __restrict__ sinT)
{
  __shared__ alignas(16) u16 As[3][128*64];   // 3 x 16 KiB
  __shared__ alignas(16) u16 Bs[3][256*64];   // 3 x 32 KiB  (total 144 KiB)

  const int B = blockIdx.x;
  const int bm = ((B & 7) << 3) | ((B >> 3) & 7);   // bijective per y
  const int y  = B >> 6;
  int proj, bnl;
  const u16* W;
  if constexpr (MODE == 0) {
    proj = y >> 2; bnl = y & 3;
    W = (proj == 0) ? W0 : (proj == 1) ? W1 : W2;
  } else {
    proj = 3; bnl = y; W = W0;
  }

  const int tid = threadIdx.x;
  const int wave = tid >> 6, lane = tid & 63;
  const int lg = lane >> 4, lr = lane & 15;
  const int wm = wave >> 2, wn = wave & 3;    // 2M x 4N wave grid

  const u16* Ab = A + (size_t)(bm*128)*DMODEL;
  const u16* Wb = W + (size_t)(bnl*256)*DMODEL;

  f32x4 acc[4][4];
#pragma unroll
  for (int i = 0; i < 4; ++i)
#pragma unroll
    for (int j = 0; j < 4; ++j) acc[i][j] = (f32x4){0,0,0,0};

  // stage one K-tile (6 gload_lds/wave): LDS[row][ch] = G[row][ch^(row&7)]
  auto stage = [&](int buf, int kt) {
    const int k0 = kt * 64;
#pragma unroll
    for (int i = 0; i < 2; ++i) {
      const int idx = i*512 + tid;          // 0..1023
      const int row = idx >> 3, ch = idx & 7;
      async_copy16(Ab + (size_t)row*DMODEL + k0 + ((ch ^ (row & 7)) * 8),
                   (char*)As[buf] + idx*16);
    }
#pragma unroll
    for (int i = 0; i < 4; ++i) {
      const int idx = i*512 + tid;          // 0..2047
      const int row = idx >> 3, ch = idx & 7;
      async_copy16(Wb + (size_t)row*DMODEL + k0 + ((ch ^ (row & 7)) * 8),
                   (char*)Bs[buf] + idx*16);
    }
  };

  const int NT = DMODEL / 64;   // 16
  stage(0, 0);
  stage(1, 1);
  asm volatile("s_waitcnt vmcnt(6)" ::: "memory");   // tile0 landed, tile1 flying
  __builtin_amdgcn_sched_barrier(0);
  __builtin_amdgcn_s_barrier();

  for (int t = 0; t < NT; ++t) {
    const int cur = t % 3;
    if (t + 2 < NT) stage((t + 2) % 3, t + 2);   // issue-ahead (depth 2)

    const u16* Aw = As[cur];
    const u16* Bw = Bs[cur];
    __builtin_amdgcn_s_setprio(1);
#pragma unroll
    for (int kk = 0; kk < 2; ++kk) {
      bf16x8 bfr[4];
#pragma unroll
      for (int ni = 0; ni < 4; ++ni) {
        const int row = wn*64 + ni*16 + lr;
        bfr[ni] = *(const bf16x8*)&Bw[row*64 + (((kk*4 + lg) ^ (row & 7)) * 8)];
      }
#pragma unroll
      for (int mi = 0; mi < 4; ++mi) {
        const int row = wm*64 + mi*16 + lr;
        bf16x8 af = *(const bf16x8*)&Aw[row*64 + (((kk*4 + lg) ^ (row & 7)) * 8)];
#pragma unroll
        for (int ni = 0; ni < 4; ++ni)
          acc[mi][ni] = __builtin_amdgcn_mfma_f32_16x16x32_bf16(af, bfr[ni], acc[mi][ni], 0, 0, 0);
      }
    }
    __builtin_amdgcn_s_setprio(0);

    if (t + 1 < NT) {
      if (t + 2 < NT) {        // 12 outstanding -> wait oldest 6 (tile t+1)
        asm volatile("s_waitcnt vmcnt(6)" ::: "memory");
      } else {                 // only tile t+1's 6 left
        asm volatile("s_waitcnt vmcnt(0)" ::: "memory");
      }
      __builtin_amdgcn_sched_barrier(0);
      __builtin_amdgcn_s_barrier();
    }
  }

  // ---- epilogue ----
#pragma unroll
  for (int mi = 0; mi < 4; ++mi) {
    const int row0 = bm*128 + wm*64 + mi*16 + lg*4;
#pragma unroll
    for (int ni = 0; ni < 4; ++ni) {
      const int col = bnl*256 + wn*64 + ni*16 + lr;
      f32x4 a = acc[mi][ni];
      if constexpr (MODE == 1) {
#pragma unroll
        for (int r = 0; r < 4; ++r) Fo[(size_t)(row0+r)*DMODEL + col] = a[r];
      } else {
        if (proj == 2) {        // V: write transposed (b,h,d,s), u16x4 in s
          const int hh = col >> 6, dd = col & 63;
          const int s0r = row0 & (SEQ-1);
          const int bb = row0 >> 11;
          u16x4 wv;
#pragma unroll
          for (int r = 0; r < 4; ++r) wv[r] = f2bf(a[r]);
          *(u16x4*)&Vto[((size_t)((bb*16+hh)*64 + dd))*SEQ + s0r] = wv;
        } else {                // Q/K: RoPE (Q additionally pre-scaled)
          u16* C = (proj == 0) ? Qo : Ko;
          const float scl = (proj == 0) ? 0.18033688f : 1.0f;  // 0.125*log2e
          const int dd = col & 63;
          const int j = dd >> 1;
          const float sgn = (dd & 1) ? 1.0f : -1.0f;
#pragma unroll
          for (int r = 0; r < 4; ++r) {
            const int s = (row0 + r) & (SEQ-1);
            float v = a[r];
            float pv = __shfl_xor(v, 1, 64);
            float c = cosT[s*32 + j], sn = sinT[s*32 + j];
            C[(size_t)(row0+r)*DMODEL + col] = f2bf((v*c + sgn*pv*sn) * scl);
          }
        }
      }
    }
  }
}

// ---------------- causal flash attention v4 + XCD remap ----------------
// Swapped-QK 32x32, K-row permutation, zero-shuffle P build, MFMA ones-trick.
// 1D grid 512: B%8 = XCD; each XCD owns 8 bh (K/V 4MB L2-resident);
// qt = 7-(B>>6) keeps LPT (heaviest q-tiles dispatched first).
__global__ __launch_bounds__(512) void k_attn(
    const u16* __restrict__ Q, const u16* __restrict__ K,
    const u16* __restrict__ Vt, u16* __restrict__ O)
{
  const int B = blockIdx.x;
  const int bh = ((B & 7) << 3) | ((B >> 3) & 7);
  const int qt = 7 - (B >> 6);
  const int b = bh >> 4, h = bh & 15;
  const int wave = threadIdx.x >> 6, lane = threadIdx.x & 63;
  const int ql = lane & 31, hi = lane >> 5, hi4 = hi * 4;
  const int R0 = qt*256 + wave*32;

  __shared__ alignas(16) u16 Ks[2][64*64];
  __shared__ alignas(16) u16 Vs[2][64*64];

  const u16* Qb = Q + (size_t)(b*SEQ)*DMODEL + h*64;
  const u16* Kb = K + (size_t)(b*SEQ)*DMODEL + h*64;
  const u16* Vb = Vt + (size_t)(bh*64)*SEQ;

  // Q as B-operand: lane holds Q[R0+ql][j*16 + hi*8 + i]
  bf16x8 qf[4];
#pragma unroll
  for (int j = 0; j < 4; ++j)
    qf[j] = *(const bf16x8*)(Qb + (size_t)(R0 + ql)*DMODEL + j*16 + hi*8);

  // ones A-fragment for l-accumulation
  union { u16x8 u; bf16x8 v; } onesu;
#pragma unroll
  for (int i = 0; i < 8; ++i) onesu.u[i] = 0x3F80;
  const bf16x8 ones = onesu.v;

  f32x16 o0 = (f32x16)(0.f), o1 = (f32x16)(0.f);   // O^T accum, d-tiles 0,1
  f32x16 lacc = (f32x16)(0.f);                     // row-sum accum (reg0 used)
  float m_run = -INFINITY;
  const float THR2 = 11.5415603f;   // 8 * log2(e)

  const int KT = (qt + 1) * 4;

  // K-row permutation: swap bits 2,3 (involution)
  const int qp = (ql & ~12) | ((ql & 4) << 1) | ((ql & 8) >> 1);

  // stage one KV tile: 512 threads x (1 K-chunk + 1 V-chunk of 16B)
  // pre-swizzled source (rule #21): LDS[row][c] = global[row][c ^ (row&7)]
  auto stage = [&](int buf, int kt) {
    const int idx = threadIdx.x;            // 0..511
    const int row = idx >> 3, ch = idx & 7;
    const int sch = (ch ^ (row & 7)) * 8;
    const int k0 = kt * 64;
    async_copy16(Kb + (size_t)(k0 + row)*DMODEL + sch, (char*)Ks[buf] + idx*16);
    async_copy16(Vb + (size_t)row*SEQ + k0 + sch,      (char*)Vs[buf] + idx*16);
  };

  stage(0, 0);
  __syncthreads();

  for (int kt = 0; kt < KT; ++kt) {
    const int cur = kt & 1;
    if (kt + 1 < KT) stage(cur ^ 1, kt + 1);

    const int k0 = kt*64;
    if (k0 <= R0 + 31) {
      const u16* Kw = Ks[cur];
      const u16* Vw = Vs[cur];

      // ---- QK^T (swapped, permuted rows): A-row ql <- K[st*32 + qp] ----
      bf16x8 ka[2][4];
#pragma unroll
      for (int st = 0; st < 2; ++st)
#pragma unroll
        for (int j = 0; j < 4; ++j) {
          const int rk = st*32 + qp;
          const int c = (2*j + hi) ^ (rk & 7);
          ka[st][j] = *(const bf16x8*)&Kw[rk*64 + c*8];
        }
      f32x16 s0 = (f32x16)(0.f), s1 = (f32x16)(0.f);
#pragma unroll
      for (int j = 0; j < 4; ++j) {
        s0 = __builtin_amdgcn_mfma_f32_32x32x16_bf16(ka[0][j], qf[j], s0, 0, 0, 0);
        s1 = __builtin_amdgcn_mfma_f32_32x32x16_bf16(ka[1][j], qf[j], s1, 0, 0, 0);
      }

      // ---- causal mask (diagonal band only); scores pre-scaled via Q ----
      if (k0 + 63 > R0) {
        const int base = k0 - R0;
#pragma unroll
        for (int r = 0; r < 16; ++r) {
          const int kl = (r & 7) + (hi << 3) + ((r & 8) << 1);  // permuted map
          s0[r] = (ql >= base + kl)      ? s0[r] : -1e30f;
          s1[r] = (ql >= base + 32 + kl) ? s1[r] : -1e30f;
        }
      }

      // ---- row max: lane-local tree + pair combine ----
      float t[16];
#pragma unroll
      for (int r = 0; r < 16; ++r) t[r] = fmaxf(s0[r], s1[r]);
#pragma unroll
      for (int w = 8; w >= 1; w >>= 1)
#pragma unroll
        for (int r = 0; r < w; ++r) t[r] = fmaxf(t[r], t[r+w]);
      const float mx = fmaxf(t[0], __shfl_xor(t[0], 32, 64));

      // ---- defer-max (T13) ----
      if (__any(mx > m_run + THR2)) {
        const float mn = fmaxf(m_run, mx);
        const float al = __builtin_exp2f(m_run - mn);
        m_run = mn;
        lacc[0] *= al;
#pragma unroll
        for (int r = 0; r < 16; ++r) { o0[r] *= al; o1[r] *= al; }
      }

      // ---- p = 2^(s - m) ----
      float e0[16], e1[16];
#pragma unroll
      for (int r = 0; r < 16; ++r) {
        e0[r] = __builtin_exp2f(s0[r] - m_run);
        e1[r] = __builtin_exp2f(s1[r] - m_run);
      }

      // ---- P^T -> bf16 B fragments: pure lane-local (permutation-aligned) --
      bf16x8 pb[4];
#pragma unroll
      for (int sl = 0; sl < 4; ++sl) {
        const float* e = (sl < 2) ? e0 : e1;
        const int o8 = (sl & 1) * 8;
        u32 w0 = cvtpk(e[o8+0], e[o8+1]);
        u32 w1 = cvtpk(e[o8+2], e[o8+3]);
        u32 w2 = cvtpk(e[o8+4], e[o8+5]);
        u32 w3 = cvtpk(e[o8+6], e[o8+7]);
        union { u32x4v u; bf16x8 v; } uu;
        uu.u = (u32x4v){w0, w1, w2, w3};
        pb[sl] = uu.v;
      }

      // ---- PV + l-accum: O^T[d][q] += V^T[d][k] P^T[k][q]; l += 1^T P ----
#pragma unroll
      for (int sl = 0; sl < 4; ++sl) {
        const int c0 = 2*sl + hi;
        const int d0 = ql,      ca = (c0 ^ (d0 & 7));
        const int d1 = 32 + ql, cb = (c0 ^ (d1 & 7));
        bf16x8 va0 = *(const bf16x8*)&Vw[d0*64 + ca*8];
        bf16x8 va1 = *(const bf16x8*)&Vw[d1*64 + cb*8];
        o0 = __builtin_amdgcn_mfma_f32_32x32x16_bf16(va0, pb[sl], o0, 0, 0, 0);
        o1 = __builtin_amdgcn_mfma_f32_32x32x16_bf16(va1, pb[sl], o1, 0, 0, 0);
        lacc = __builtin_amdgcn_mfma_f32_32x32x16_bf16(ones, pb[sl], lacc, 0, 0, 0);
      }
    }
    __syncthreads();
  }

  // ---- epilogue: O[q][d], packed 4-wide stores ----
  const float inv = 1.0f / lacc[0];
  u16* Orow = O + (size_t)(b*SEQ + R0 + ql)*DMODEL + h*64;
#pragma unroll
  for (int rb = 0; rb < 4; ++rb) {
    u16x4 wA, wB;
#pragma unroll
    for (int j = 0; j < 4; ++j) {
      wA[j] = f2bf(o0[rb*4 + j] * inv);
      wB[j] = f2bf(o1[rb*4 + j] * inv);
    }
    *(u16x4*)(Orow + 8*rb + hi4)      = wA;
    *(u16x4*)(Orow + 32 + 8*rb + hi4) = wB;
  }
}

// ---------------- launch ----------------
extern "C" void kernel_launch(void* const* d_in, const int* in_sizes, int n_in,
                              void* d_out, int out_size, void* d_ws, size_t ws_size,
                              hipStream_t stream) {
  const float* x  = (const float*)d_in[0];
  const float* Wq = (const float*)d_in[1];
  const float* Wk = (const float*)d_in[2];
  const float* Wv = (const float*)d_in[3];
  const float* Wo = (const float*)d_in[4];
  const int* pos  = (const int*)d_in[5];
  float* out = (float*)d_out;

  const size_t SZ_X   = (size_t)MROWS*DMODEL*2;   // 16 MiB
  const size_t SZ_W   = (size_t)DMODEL*DMODEL*2;  // 2 MiB
  const size_t SZ_TAB = (size_t)SEQ*32*4;
  char* w = (char*)d_ws;
  u16* xb   = (u16*)(w);
  u16* Wqb  = (u16*)(w + SZ_X);
  u16* Wkb  = (u16*)(w + SZ_X + SZ_W);
  u16* Wvb  = (u16*)(w + SZ_X + 2*SZ_W);
  u16* Wob  = (u16*)(w + SZ_X + 3*SZ_W);
  float* cosT = (float*)(w + SZ_X + 4*SZ_W);
  float* sinT = (float*)(w + SZ_X + 4*SZ_W + SZ_TAB);
  u16* Qb   = (u16*)(w + SZ_X + 4*SZ_W + 2*SZ_TAB);
  u16* Kb   = (u16*)(w + 2*SZ_X + 4*SZ_W + 2*SZ_TAB);
  u16* Ob   = (u16*)(w + 3*SZ_X + 4*SZ_W + 2*SZ_TAB);
  u16* Vt   = (u16*)(w + 4*SZ_X + 4*SZ_W + 2*SZ_TAB);
  const size_t need = 5*SZ_X + 4*SZ_W + 2*SZ_TAB;
  if (ws_size < need) return;

  k_prep<<<12544, 256, 0, stream>>>(x, Wq, Wk, Wv, Wo, pos,
                                    xb, Wqb, Wkb, Wvb, Wob, cosT, sinT);
  k_gemm2<0><<<768, 512, 0, stream>>>(
      xb, Wqb, Wkb, Wvb, Qb, Kb, Vt, nullptr, cosT, sinT);
  k_attn<<<512, 512, 0, stream>>>(Qb, Kb, Vt, Ob);
  k_gemm2<1><<<256, 512, 0, stream>>>(
      Ob, Wob, nullptr, nullptr, nullptr, nullptr, nullptr, out, cosT, sinT);
}